// Round 7
// baseline (297.198 us; speedup 1.0000x reference)
//
#include <hip/hip_runtime.h>

#define H 4
#define C 128
#define FOUT 512

typedef __attribute__((ext_vector_type(8))) short s16x8;
typedef __attribute__((ext_vector_type(4))) float f32x4;
typedef __attribute__((ext_vector_type(4))) int i32x4;
typedef __attribute__((ext_vector_type(2))) int i32x2;

// CK-style raw buffer-load intrinsics (32-bit voffset addressing)
__device__ int amd_buf_load_i32(i32x4 rsrc, int voffset, int soffset, int aux) __asm("llvm.amdgcn.raw.buffer.load.i32");
__device__ i32x2 amd_buf_load_i32x2(i32x4 rsrc, int voffset, int soffset, int aux) __asm("llvm.amdgcn.raw.buffer.load.v2i32");

__device__ __forceinline__ i32x4 make_rsrc(const void* p, unsigned int bytes) {
    i32x4 r;
    r.x = (int)(unsigned int)(unsigned long long)p;
    r.y = (int)(unsigned int)(((unsigned long long)p) >> 32);
    r.z = (int)bytes;          // num_records (stride==0 -> bytes); OOB load returns 0
    r.w = 0x00020000;          // raw untyped dword access
    return r;
}

__device__ __forceinline__ unsigned int f2bf_bits(float f) {
    unsigned int u = __float_as_uint(f);
    u += 0x7fffu + ((u >> 16) & 1u);
    return u >> 16;
}
__device__ __forceinline__ float bflo(unsigned int u) { return __uint_as_float(u << 16); }
__device__ __forceinline__ float bfhi(unsigned int u) { return __uint_as_float(u & 0xffff0000u); }
__device__ __forceinline__ float leaky(float x) { return (x >= 0.f) ? x : 0.2f * x; }

// ---------------- CSR build ----------------
__global__ void zero_i32(int* __restrict__ p, int n) {
    int i = blockIdx.x * blockDim.x + threadIdx.x;
    if (i < n) p[i] = 0;
}

__global__ void hist_kernel(const int* __restrict__ ei, int E, int N, int* __restrict__ counts) {
    int e = blockIdx.x * blockDim.x + threadIdx.x;
    int M = E + N;
    if (e >= M) return;
    int d = (e < E) ? ei[E + e] : (e - E);
    atomicAdd(&counts[d], 1);
}

__global__ __launch_bounds__(256) void scan_kernel(const int* __restrict__ counts,
                                                   int* __restrict__ row_off,
                                                   int* __restrict__ cursor, int N) {
    __shared__ int part[256];
    int t = threadIdx.x;
    int chunk = (N + 255) >> 8;
    int b = t * chunk; if (b > N) b = N;
    int e = b + chunk; if (e > N) e = N;
    int s = 0;
    for (int i = b; i < e; ++i) s += counts[i];
    part[t] = s;
    __syncthreads();
    for (int off = 1; off < 256; off <<= 1) {
        int v = (t >= off) ? part[t - off] : 0;
        __syncthreads();
        part[t] += v;
        __syncthreads();
    }
    int run = (t == 0) ? 0 : part[t - 1];
    for (int i = b; i < e; ++i) { row_off[i] = run; cursor[i] = run; run += counts[i]; }
    if (t == 255) row_off[N] = part[255];
}

__global__ void scatter_kernel(const int* __restrict__ ei, int E, int N,
                               int* __restrict__ cursor, int* __restrict__ csr_src) {
    int e = blockIdx.x * blockDim.x + threadIdx.x;
    int M = E + N;
    if (e >= M) return;
    int s = (e < E) ? ei[e] : (e - E);
    int d = (e < E) ? ei[E + e] : (e - E);
    int pos = atomicAdd(&cursor[d], 1);
    csr_src[pos] = s;
}

// ---------------- input conversions ----------------
__global__ void convert_x(const float* __restrict__ x, unsigned short* __restrict__ xA,
                          unsigned short* __restrict__ featsbf, float2* __restrict__ coords,
                          int N, int Npad) {
    int i = blockIdx.x * blockDim.x + threadIdx.x;  // one 4-channel group per thread
    int total = Npad * (C / 4);
    if (i >= total) return;
    int row = i >> 5;
    int c4 = (i & 31) * 4;
    ushort4 o;
    if (row < N) {
        const float* p = x + (size_t)row * 130 + 2 + c4;
        float2 v0 = *(const float2*)p;
        float2 v1 = *(const float2*)(p + 2);
        o.x = (unsigned short)f2bf_bits(v0.x);
        o.y = (unsigned short)f2bf_bits(v0.y);
        o.z = (unsigned short)f2bf_bits(v1.x);
        o.w = (unsigned short)f2bf_bits(v1.y);
        if ((i & 31) == 0) coords[row] = *(const float2*)&x[(size_t)row * 130];
    } else {
        o = make_ushort4(0, 0, 0, 0);
        *(ushort4*)&featsbf[(size_t)row * C + c4] = o;   // zero pad rows of layer-2 input
    }
    *(ushort4*)&xA[(size_t)row * C + c4] = o;
}

__global__ void convert_w(const float* __restrict__ W1, const float* __restrict__ W2,
                          unsigned short* __restrict__ Wt1, unsigned short* __restrict__ Wt2) {
    int i = blockIdx.x * blockDim.x + threadIdx.x;
    if (i >= 128 * 512) return;
    int c = i >> 7, k = i & 127;
    Wt1[i] = (unsigned short)f2bf_bits(W1[(size_t)k * FOUT + c]);
    Wt2[i] = (unsigned short)f2bf_bits(W2[(size_t)k * FOUT + c]);
}

// ---------------- MFMA GEMM (direct global->VGPR fragments) + fused alpha ----------------
// A [Npad][128] bf16 row-major, Bt [512][128] bf16 (col-major weights). Fragments are
// 16B-contiguous in both -> no input LDS staging. LDS only for C transpose (32 KB).
__global__ __launch_bounds__(256) void gemm_direct(const unsigned short* __restrict__ A,
                                                   const unsigned short* __restrict__ Bt,
                                                   const float* __restrict__ a_src,
                                                   const float* __restrict__ a_dst,
                                                   unsigned short* __restrict__ Cb,
                                                   float* __restrict__ alpha_s,
                                                   float* __restrict__ alpha_d,
                                                   int Nrows, int Npad) {
    __shared__ unsigned short Cs[128 * 128];  // C transpose staging, 16B-chunk XOR-swizzled
    int t = threadIdx.x;
    int lane = t & 63;
    int wv = t >> 6;
    int wr = wv >> 1, wc = wv & 1;
    int lr = lane & 15;
    int ksel = lane >> 4;
    int h = blockIdx.x;
    int r0 = blockIdx.y * 128;

    f32x4 acc[4][4];
    #pragma unroll
    for (int i = 0; i < 4; ++i)
        #pragma unroll
        for (int j = 0; j < 4; ++j) acc[i][j] = (f32x4){0.f, 0.f, 0.f, 0.f};

    const s16x8* Abase = (const s16x8*)(A + (size_t)(r0 + wr * 64 + lr) * C);
    const s16x8* Bbase = (const s16x8*)(Bt + (size_t)(h * 128 + wc * 64 + lr) * C);

    #pragma unroll
    for (int ks = 0; ks < 4; ++ks) {
        int cb = ks * 4 + ksel;
        s16x8 af[4], bf[4];
        #pragma unroll
        for (int i = 0; i < 4; ++i) {
            af[i] = Abase[(size_t)(i * 16) * 16 + cb];   // row += i*16 -> i*16*(C/8) s16x8
            bf[i] = Bbase[(size_t)(i * 16) * 16 + cb];
        }
        #pragma unroll
        for (int i = 0; i < 4; ++i)
            #pragma unroll
            for (int j = 0; j < 4; ++j)
                acc[i][j] = __builtin_amdgcn_mfma_f32_16x16x32_bf16(af[i], bf[j], acc[i][j], 0, 0, 0);
    }

    // transpose C frags into Cs as bf16 [row][col], byte-swizzled
    #pragma unroll
    for (int i = 0; i < 4; ++i) {
        #pragma unroll
        for (int j = 0; j < 4; ++j) {
            int col = wc * 64 + j * 16 + lr;
            #pragma unroll
            for (int r = 0; r < 4; ++r) {
                int row = wr * 64 + i * 16 + ksel * 4 + r;
                int boff = (row * 256 + col * 2) ^ ((row & 7) << 4);
                *(unsigned short*)((char*)Cs + boff) = (unsigned short)f2bf_bits(acc[i][j][r]);
            }
        }
    }
    __syncthreads();

    // coalesced store (slab layout) + fused alpha reduction
    int cb = t & 15, rb = t >> 4;
    float4 av0 = *(const float4*)&a_src[h * C + cb * 8];
    float4 av1 = *(const float4*)&a_src[h * C + cb * 8 + 4];
    float4 dv0 = *(const float4*)&a_dst[h * C + cb * 8];
    float4 dv1 = *(const float4*)&a_dst[h * C + cb * 8 + 4];
    #pragma unroll
    for (int i = 0; i < 8; ++i) {
        int row = rb + i * 16;
        uint4 v = ((const uint4*)Cs)[row * 16 + (cb ^ (row & 7))];
        float f0 = bflo(v.x), f1 = bfhi(v.x), f2 = bflo(v.y), f3 = bfhi(v.y);
        float f4 = bflo(v.z), f5 = bfhi(v.z), f6 = bflo(v.w), f7 = bfhi(v.w);
        float ps = f0 * av0.x + f1 * av0.y + f2 * av0.z + f3 * av0.w
                 + f4 * av1.x + f5 * av1.y + f6 * av1.z + f7 * av1.w;
        float pd = f0 * dv0.x + f1 * dv0.y + f2 * dv0.z + f3 * dv0.w
                 + f4 * dv1.x + f5 * dv1.y + f6 * dv1.z + f7 * dv1.w;
        ps += __shfl_xor(ps, 1); pd += __shfl_xor(pd, 1);
        ps += __shfl_xor(ps, 2); pd += __shfl_xor(pd, 2);
        ps += __shfl_xor(ps, 4); pd += __shfl_xor(pd, 4);
        ps += __shfl_xor(ps, 8); pd += __shfl_xor(pd, 8);
        int gr = r0 + row;
        if (gr < Nrows) {
            ((uint4*)Cb)[((size_t)(h * 2 + (cb >> 3)) * Npad + gr) * 8 + (cb & 7)] = v;
            if (cb == 0) {
                alpha_s[gr * H + h] = ps;
                alpha_d[gr * H + h] = pd;
            }
        }
    }
}

// ---------------- fused per-node max + per-edge weights ----------------
// pass1: m_h = leaky(max_src(as) + ad) (monotone leaky trick); pass2 (L1-warm): pk[h][e] = {src, exp(..)-m}
__global__ __launch_bounds__(256) void attn_kernel(const float4* __restrict__ as4,
                                                   const float4* __restrict__ ad4,
                                                   const int* __restrict__ row_off,
                                                   const int* __restrict__ csr_src,
                                                   uint2* __restrict__ pk, int N, int M) {
    int n = blockIdx.x * 4 + (threadIdx.x >> 6);
    if (n >= N) return;
    int l = threadIdx.x & 63;
    int beg = row_off[n], end = row_off[n + 1];
    float4 mx = make_float4(-1e30f, -1e30f, -1e30f, -1e30f);
    for (int e = beg + l; e < end; e += 64) {
        float4 a = as4[csr_src[e]];
        mx.x = fmaxf(mx.x, a.x); mx.y = fmaxf(mx.y, a.y);
        mx.z = fmaxf(mx.z, a.z); mx.w = fmaxf(mx.w, a.w);
    }
    #pragma unroll
    for (int off = 32; off >= 1; off >>= 1) {
        mx.x = fmaxf(mx.x, __shfl_xor(mx.x, off));
        mx.y = fmaxf(mx.y, __shfl_xor(mx.y, off));
        mx.z = fmaxf(mx.z, __shfl_xor(mx.z, off));
        mx.w = fmaxf(mx.w, __shfl_xor(mx.w, off));
    }
    float4 d = ad4[n];
    float4 m;
    m.x = leaky(mx.x + d.x); m.y = leaky(mx.y + d.y);
    m.z = leaky(mx.z + d.z); m.w = leaky(mx.w + d.w);
    for (int e = beg + l; e < end; e += 64) {
        int s = csr_src[e];
        float4 a = as4[s];
        unsigned int su = (unsigned int)s;
        pk[e]                 = make_uint2(su, __float_as_uint(__expf(leaky(a.x + d.x) - m.x)));
        pk[(size_t)M + e]     = make_uint2(su, __float_as_uint(__expf(leaky(a.y + d.y) - m.y)));
        pk[(size_t)2 * M + e] = make_uint2(su, __float_as_uint(__expf(leaky(a.z + d.z) - m.z)));
        pk[(size_t)3 * M + e] = make_uint2(su, __float_as_uint(__expf(leaky(a.w + d.w) - m.w)));
    }
}

// ---------------- aggregation: XCD-pinned slabs, triple-buffered pk prefetch, uniform loop ----------------
__global__ __launch_bounds__(256) void aggregate_v7(const unsigned short* __restrict__ xh_bf,
                                                    const uint2* __restrict__ pk,
                                                    const int* __restrict__ row_off,
                                                    unsigned short* __restrict__ hout,
                                                    int N, int Npad, int M) {
    int i = blockIdx.x;
    int slab = i & 7;
    int h = slab >> 1;
    int t = threadIdx.x;
    int n = (i >> 3) * 8 + ((t >> 6) << 1) + ((t >> 5) & 1);
    if (n >= N) return;
    int ld4 = (t & 31) << 2;
    int beg = row_off[n], end = row_off[n + 1];

    i32x4 rx = make_rsrc(xh_bf + (size_t)slab * Npad * 64, (unsigned int)Npad * 128u);
    i32x4 rp = make_rsrc(pk + (size_t)h * M, (unsigned int)M * 8u);

    float acc0 = 0.f, acc1 = 0.f, acc2 = 0.f, acc3 = 0.f, den0 = 0.f, den1 = 0.f;
    int vo = beg << 3;
    i32x2 pa0 = amd_buf_load_i32x2(rp, vo, 0, 0);
    i32x2 pa1 = amd_buf_load_i32x2(rp, vo + 8, 0, 0);
    i32x2 pa2 = amd_buf_load_i32x2(rp, vo + 16, 0, 0);
    i32x2 pa3 = amd_buf_load_i32x2(rp, vo + 24, 0, 0);
    i32x2 pb0 = amd_buf_load_i32x2(rp, vo + 32, 0, 0);
    i32x2 pb1 = amd_buf_load_i32x2(rp, vo + 40, 0, 0);
    i32x2 pb2 = amd_buf_load_i32x2(rp, vo + 48, 0, 0);
    i32x2 pb3 = amd_buf_load_i32x2(rp, vo + 56, 0, 0);
    i32x2 pc0 = amd_buf_load_i32x2(rp, vo + 64, 0, 0);
    i32x2 pc1 = amd_buf_load_i32x2(rp, vo + 72, 0, 0);
    i32x2 pc2 = amd_buf_load_i32x2(rp, vo + 80, 0, 0);
    i32x2 pc3 = amd_buf_load_i32x2(rp, vo + 88, 0, 0);
    vo += 96;
    int iters = (end - beg + 3) >> 2;
    int e = beg;
    for (int it = 0; it < iters; ++it) {
        unsigned int v0 = (unsigned int)amd_buf_load_i32(rx, (pa0.x << 7) + ld4, 0, 0);
        unsigned int v1 = (unsigned int)amd_buf_load_i32(rx, (pa1.x << 7) + ld4, 0, 0);
        unsigned int v2 = (unsigned int)amd_buf_load_i32(rx, (pa2.x << 7) + ld4, 0, 0);
        unsigned int v3 = (unsigned int)amd_buf_load_i32(rx, (pa3.x << 7) + ld4, 0, 0);
        float w0 = (e < end)     ? __uint_as_float((unsigned int)pa0.y) : 0.f;
        float w1 = (e + 1 < end) ? __uint_as_float((unsigned int)pa1.y) : 0.f;
        float w2 = (e + 2 < end) ? __uint_as_float((unsigned int)pa2.y) : 0.f;
        float w3 = (e + 3 < end) ? __uint_as_float((unsigned int)pa3.y) : 0.f;
        pa0 = pb0; pa1 = pb1; pa2 = pb2; pa3 = pb3;
        pb0 = pc0; pb1 = pc1; pb2 = pc2; pb3 = pc3;
        pc0 = amd_buf_load_i32x2(rp, vo, 0, 0);
        pc1 = amd_buf_load_i32x2(rp, vo + 8, 0, 0);
        pc2 = amd_buf_load_i32x2(rp, vo + 16, 0, 0);
        pc3 = amd_buf_load_i32x2(rp, vo + 24, 0, 0);
        vo += 32;
        den0 += w0 + w2; den1 += w1 + w3;
        acc0 += w0 * bflo(v0); acc1 += w0 * bfhi(v0);
        acc2 += w1 * bflo(v1); acc3 += w1 * bfhi(v1);
        acc0 += w2 * bflo(v2); acc1 += w2 * bfhi(v2);
        acc2 += w3 * bflo(v3); acc3 += w3 * bfhi(v3);
        e += 4;
    }
    float inv = 1.f / (den0 + den1);
    unsigned int o = f2bf_bits((acc0 + acc2) * inv) | (f2bf_bits((acc1 + acc3) * inv) << 16);
    ((unsigned int*)hout)[((size_t)slab * Npad + n) * 32 + (t & 31)] = o;
}

// ---------------- head mean + bias -> bf16 feats ----------------
__global__ void combine_kernel(const unsigned short* __restrict__ hout,
                               const float* __restrict__ bias,
                               unsigned short* __restrict__ featsbf, int N, int Npad) {
    int i = blockIdx.x * blockDim.x + threadIdx.x;   // dword index over [N][64]
    if (i >= N * 64) return;
    int n = i >> 6, c2 = i & 63;
    int chalf = c2 >> 5, ld = c2 & 31;
    const unsigned int* hp = (const unsigned int*)hout;
    float lo = 0.f, hi = 0.f;
    #pragma unroll
    for (int h = 0; h < 4; ++h) {
        unsigned int v = hp[((size_t)(h * 2 + chalf) * Npad + n) * 32 + ld];
        lo += bflo(v); hi += bfhi(v);
    }
    lo = 0.25f * lo + bias[c2 * 2];
    hi = 0.25f * hi + bias[c2 * 2 + 1];
    ((unsigned int*)featsbf)[(size_t)n * 64 + c2] = f2bf_bits(lo) | (f2bf_bits(hi) << 16);
}

// ---------------- pairwise scorer (bf16 feats, packed coords) ----------------
__global__ __launch_bounds__(256) void pair_kernel(const unsigned short* __restrict__ featsbf,
                                                   const float2* __restrict__ coords,
                                                   const int* __restrict__ idx, int P,
                                                   const float* __restrict__ fc_w,
                                                   const float* __restrict__ fc_b,
                                                   float* __restrict__ out) {
    int p = blockIdx.x * 4 + (threadIdx.x >> 6);
    int l = threadIdx.x & 63;
    if (p >= P) return;
    int i0 = idx[p], i1 = idx[P + p];
    unsigned int a = ((const unsigned int*)featsbf)[(size_t)i0 * 64 + l];
    unsigned int b = ((const unsigned int*)featsbf)[(size_t)i1 * 64 + l];
    float s = bflo(a) * bflo(b) + bfhi(a) * bfhi(b);
    #pragma unroll
    for (int off = 32; off >= 1; off >>= 1) s += __shfl_xor(s, off);
    if (l == 0) {
        float2 c0 = coords[i0], c1 = coords[i1];
        float dx = c0.x - c1.x;
        float dy = c0.y - c1.y;
        float pe = dx * dx + dy * dy;
        out[p] = fc_w[0] * s + fc_w[1] * pe + fc_b[0];
    }
}

extern "C" void kernel_launch(void* const* d_in, const int* in_sizes, int n_in,
                              void* d_out, int out_size, void* d_ws, size_t ws_size,
                              hipStream_t stream) {
    const float* x   = (const float*)d_in[0];
    const int*   ei  = (const int*)d_in[1];
    const int*   idx = (const int*)d_in[2];
    const float* W1  = (const float*)d_in[3];
    const float* as1 = (const float*)d_in[4];
    const float* ad1 = (const float*)d_in[5];
    const float* b1  = (const float*)d_in[6];
    const float* W2  = (const float*)d_in[7];
    const float* as2 = (const float*)d_in[8];
    const float* ad2 = (const float*)d_in[9];
    const float* b2  = (const float*)d_in[10];
    const float* fcw = (const float*)d_in[11];
    const float* fcb = (const float*)d_in[12];
    float* out = (float*)d_out;

    const int N = in_sizes[0] / 130;
    const int E = in_sizes[1] / 2;
    const int P = in_sizes[2] / 2;
    const int M = E + N;
    const int Npad = (N + 127) & ~127;

    char* ws = (char*)d_ws;
    size_t off = 0;
    auto alloc = [&](size_t bytes) -> void* {
        void* p = ws + off;
        off += (bytes + 255) & ~(size_t)255;
        return p;
    };
    unsigned short* xh_bf   = (unsigned short*)alloc((size_t)Npad * FOUT * 2);
    unsigned short* hout    = (unsigned short*)alloc((size_t)Npad * FOUT * 2);
    unsigned short* xA      = (unsigned short*)alloc((size_t)Npad * C * 2);
    unsigned short* featsbf = (unsigned short*)alloc((size_t)Npad * C * 2);
    unsigned short* Wt1     = (unsigned short*)alloc((size_t)128 * FOUT * 2);
    unsigned short* Wt2     = (unsigned short*)alloc((size_t)128 * FOUT * 2);
    float*          alpha_s = (float*)alloc((size_t)N * H * 4);
    float*          alpha_d = (float*)alloc((size_t)N * H * 4);
    float2*         coords  = (float2*)alloc((size_t)N * 8);
    uint2*          pk      = (uint2*)alloc((size_t)M * H * 8);
    int*            row_off = (int*)alloc((size_t)(N + 1) * 4);
    int*            cursor  = (int*)alloc((size_t)N * 4);
    int*            counts  = (int*)alloc((size_t)N * 4);
    int*            csr_src = (int*)alloc((size_t)M * 4);

    // CSR by dst (shared across both layers)
    zero_i32<<<(N + 255) / 256, 256, 0, stream>>>(counts, N);
    hist_kernel<<<(M + 255) / 256, 256, 0, stream>>>(ei, E, N, counts);
    scan_kernel<<<1, 256, 0, stream>>>(counts, row_off, cursor, N);
    scatter_kernel<<<(M + 255) / 256, 256, 0, stream>>>(ei, E, N, cursor, csr_src);

    // input conversions
    convert_x<<<(Npad * (C / 4) + 255) / 256, 256, 0, stream>>>(x, xA, featsbf, coords, N, Npad);
    convert_w<<<(128 * FOUT + 255) / 256, 256, 0, stream>>>(W1, W2, Wt1, Wt2);

    dim3 ggrid(H, Npad / 128);
    int aggGrid = ((N + 7) / 8) * 8;
    int cmbGrid = (N * 64 + 255) / 256;

    // layer 1
    gemm_direct<<<ggrid, 256, 0, stream>>>(xA, Wt1, as1, ad1, xh_bf, alpha_s, alpha_d, N, Npad);
    attn_kernel<<<(N + 3) / 4, 256, 0, stream>>>((const float4*)alpha_s, (const float4*)alpha_d,
                                                 row_off, csr_src, pk, N, M);
    aggregate_v7<<<aggGrid, 256, 0, stream>>>(xh_bf, pk, row_off, hout, N, Npad, M);
    combine_kernel<<<cmbGrid, 256, 0, stream>>>(hout, b1, featsbf, N, Npad);

    // layer 2
    gemm_direct<<<ggrid, 256, 0, stream>>>(featsbf, Wt2, as2, ad2, xh_bf, alpha_s, alpha_d, N, Npad);
    attn_kernel<<<(N + 3) / 4, 256, 0, stream>>>((const float4*)alpha_s, (const float4*)alpha_d,
                                                 row_off, csr_src, pk, N, M);
    aggregate_v7<<<aggGrid, 256, 0, stream>>>(xh_bf, pk, row_off, hout, N, Npad, M);
    combine_kernel<<<cmbGrid, 256, 0, stream>>>(hout, b2, featsbf, N, Npad);

    // pairwise output
    pair_kernel<<<(P + 3) / 4, 256, 0, stream>>>(featsbf, coords, idx, P, fcw, fcb, out);
}

// Round 8
// 286.626 us; speedup vs baseline: 1.0369x; 1.0369x over previous
//
#include <hip/hip_runtime.h>

#define H 4
#define C 128
#define FOUT 512

typedef __attribute__((ext_vector_type(8))) short s16x8;
typedef __attribute__((ext_vector_type(4))) float f32x4;
typedef __attribute__((ext_vector_type(4))) int i32x4;
typedef __attribute__((ext_vector_type(2))) int i32x2;

// CK-style raw buffer-load intrinsics (32-bit voffset addressing)
__device__ int amd_buf_load_i32(i32x4 rsrc, int voffset, int soffset, int aux) __asm("llvm.amdgcn.raw.buffer.load.i32");
__device__ i32x2 amd_buf_load_i32x2(i32x4 rsrc, int voffset, int soffset, int aux) __asm("llvm.amdgcn.raw.buffer.load.v2i32");

__device__ __forceinline__ i32x4 make_rsrc(const void* p, unsigned int bytes) {
    i32x4 r;
    r.x = (int)(unsigned int)(unsigned long long)p;
    r.y = (int)(unsigned int)(((unsigned long long)p) >> 32);
    r.z = (int)bytes;          // num_records (stride==0 -> bytes); OOB load returns 0
    r.w = 0x00020000;          // raw untyped dword access
    return r;
}

__device__ __forceinline__ unsigned int f2bf_bits(float f) {
    unsigned int u = __float_as_uint(f);
    u += 0x7fffu + ((u >> 16) & 1u);
    return u >> 16;
}
__device__ __forceinline__ float bflo(unsigned int u) { return __uint_as_float(u << 16); }
__device__ __forceinline__ float bfhi(unsigned int u) { return __uint_as_float(u & 0xffff0000u); }
__device__ __forceinline__ float leaky(float x) { return (x >= 0.f) ? x : 0.2f * x; }

// ---------------- CSR build ----------------
__global__ void zero_i32(int* __restrict__ p, int n) {
    int i = blockIdx.x * blockDim.x + threadIdx.x;
    if (i < n) p[i] = 0;
}

__global__ void hist_kernel(const int* __restrict__ ei, int E, int N, int* __restrict__ counts) {
    int e = blockIdx.x * blockDim.x + threadIdx.x;
    int M = E + N;
    if (e >= M) return;
    int d = (e < E) ? ei[E + e] : (e - E);
    atomicAdd(&counts[d], 1);
}

__global__ __launch_bounds__(256) void scan_kernel(const int* __restrict__ counts,
                                                   int* __restrict__ row_off,
                                                   int* __restrict__ cursor, int N) {
    __shared__ int part[256];
    int t = threadIdx.x;
    int chunk = (N + 255) >> 8;
    int b = t * chunk; if (b > N) b = N;
    int e = b + chunk; if (e > N) e = N;
    int s = 0;
    for (int i = b; i < e; ++i) s += counts[i];
    part[t] = s;
    __syncthreads();
    for (int off = 1; off < 256; off <<= 1) {
        int v = (t >= off) ? part[t - off] : 0;
        __syncthreads();
        part[t] += v;
        __syncthreads();
    }
    int run = (t == 0) ? 0 : part[t - 1];
    for (int i = b; i < e; ++i) { row_off[i] = run; cursor[i] = run; run += counts[i]; }
    if (t == 255) row_off[N] = part[255];
}

__global__ void scatter_kernel(const int* __restrict__ ei, int E, int N,
                               int* __restrict__ cursor, int* __restrict__ csr_src) {
    int e = blockIdx.x * blockDim.x + threadIdx.x;
    int M = E + N;
    if (e >= M) return;
    int s = (e < E) ? ei[e] : (e - E);
    int d = (e < E) ? ei[E + e] : (e - E);
    int pos = atomicAdd(&cursor[d], 1);
    csr_src[pos] = s;
}

// ---------------- input conversions ----------------
__global__ void convert_x(const float* __restrict__ x, unsigned short* __restrict__ xA,
                          unsigned short* __restrict__ featsbf, float2* __restrict__ coords,
                          int N, int Npad) {
    int i = blockIdx.x * blockDim.x + threadIdx.x;  // one 4-channel group per thread
    int total = Npad * (C / 4);
    if (i >= total) return;
    int row = i >> 5;
    int c4 = (i & 31) * 4;
    ushort4 o;
    if (row < N) {
        const float* p = x + (size_t)row * 130 + 2 + c4;
        float2 v0 = *(const float2*)p;
        float2 v1 = *(const float2*)(p + 2);
        o.x = (unsigned short)f2bf_bits(v0.x);
        o.y = (unsigned short)f2bf_bits(v0.y);
        o.z = (unsigned short)f2bf_bits(v1.x);
        o.w = (unsigned short)f2bf_bits(v1.y);
        if ((i & 31) == 0) coords[row] = *(const float2*)&x[(size_t)row * 130];
    } else {
        o = make_ushort4(0, 0, 0, 0);
        *(ushort4*)&featsbf[(size_t)row * C + c4] = o;   // zero pad rows of layer-2 input
    }
    *(ushort4*)&xA[(size_t)row * C + c4] = o;
}

__global__ void convert_w(const float* __restrict__ W1, const float* __restrict__ W2,
                          unsigned short* __restrict__ Wt1, unsigned short* __restrict__ Wt2) {
    int i = blockIdx.x * blockDim.x + threadIdx.x;
    if (i >= 128 * 512) return;
    int c = i >> 7, k = i & 127;
    Wt1[i] = (unsigned short)f2bf_bits(W1[(size_t)k * FOUT + c]);
    Wt2[i] = (unsigned short)f2bf_bits(W2[(size_t)k * FOUT + c]);
}

// ---------------- MFMA GEMM (direct global->VGPR fragments) + fused alpha ----------------
__global__ __launch_bounds__(256) void gemm_direct(const unsigned short* __restrict__ A,
                                                   const unsigned short* __restrict__ Bt,
                                                   const float* __restrict__ a_src,
                                                   const float* __restrict__ a_dst,
                                                   unsigned short* __restrict__ Cb,
                                                   float* __restrict__ alpha_s,
                                                   float* __restrict__ alpha_d,
                                                   int Nrows, int Npad) {
    __shared__ unsigned short Cs[128 * 128];  // C transpose staging, 16B-chunk XOR-swizzled
    int t = threadIdx.x;
    int lane = t & 63;
    int wv = t >> 6;
    int wr = wv >> 1, wc = wv & 1;
    int lr = lane & 15;
    int ksel = lane >> 4;
    int h = blockIdx.x;
    int r0 = blockIdx.y * 128;

    f32x4 acc[4][4];
    #pragma unroll
    for (int i = 0; i < 4; ++i)
        #pragma unroll
        for (int j = 0; j < 4; ++j) acc[i][j] = (f32x4){0.f, 0.f, 0.f, 0.f};

    const s16x8* Abase = (const s16x8*)(A + (size_t)(r0 + wr * 64 + lr) * C);
    const s16x8* Bbase = (const s16x8*)(Bt + (size_t)(h * 128 + wc * 64 + lr) * C);

    #pragma unroll
    for (int ks = 0; ks < 4; ++ks) {
        int cb = ks * 4 + ksel;
        s16x8 af[4], bf[4];
        #pragma unroll
        for (int i = 0; i < 4; ++i) {
            af[i] = Abase[(size_t)(i * 16) * 16 + cb];
            bf[i] = Bbase[(size_t)(i * 16) * 16 + cb];
        }
        #pragma unroll
        for (int i = 0; i < 4; ++i)
            #pragma unroll
            for (int j = 0; j < 4; ++j)
                acc[i][j] = __builtin_amdgcn_mfma_f32_16x16x32_bf16(af[i], bf[j], acc[i][j], 0, 0, 0);
    }

    // transpose C frags into Cs as bf16 [row][col], byte-swizzled
    #pragma unroll
    for (int i = 0; i < 4; ++i) {
        #pragma unroll
        for (int j = 0; j < 4; ++j) {
            int col = wc * 64 + j * 16 + lr;
            #pragma unroll
            for (int r = 0; r < 4; ++r) {
                int row = wr * 64 + i * 16 + ksel * 4 + r;
                int boff = (row * 256 + col * 2) ^ ((row & 7) << 4);
                *(unsigned short*)((char*)Cs + boff) = (unsigned short)f2bf_bits(acc[i][j][r]);
            }
        }
    }
    __syncthreads();

    // coalesced store (slab layout) + fused alpha reduction
    int cb = t & 15, rb = t >> 4;
    float4 av0 = *(const float4*)&a_src[h * C + cb * 8];
    float4 av1 = *(const float4*)&a_src[h * C + cb * 8 + 4];
    float4 dv0 = *(const float4*)&a_dst[h * C + cb * 8];
    float4 dv1 = *(const float4*)&a_dst[h * C + cb * 8 + 4];
    #pragma unroll
    for (int i = 0; i < 8; ++i) {
        int row = rb + i * 16;
        uint4 v = ((const uint4*)Cs)[row * 16 + (cb ^ (row & 7))];
        float f0 = bflo(v.x), f1 = bfhi(v.x), f2 = bflo(v.y), f3 = bfhi(v.y);
        float f4 = bflo(v.z), f5 = bfhi(v.z), f6 = bflo(v.w), f7 = bfhi(v.w);
        float ps = f0 * av0.x + f1 * av0.y + f2 * av0.z + f3 * av0.w
                 + f4 * av1.x + f5 * av1.y + f6 * av1.z + f7 * av1.w;
        float pd = f0 * dv0.x + f1 * dv0.y + f2 * dv0.z + f3 * dv0.w
                 + f4 * dv1.x + f5 * dv1.y + f6 * dv1.z + f7 * dv1.w;
        ps += __shfl_xor(ps, 1); pd += __shfl_xor(pd, 1);
        ps += __shfl_xor(ps, 2); pd += __shfl_xor(pd, 2);
        ps += __shfl_xor(ps, 4); pd += __shfl_xor(pd, 4);
        ps += __shfl_xor(ps, 8); pd += __shfl_xor(pd, 8);
        int gr = r0 + row;
        if (gr < Nrows) {
            ((uint4*)Cb)[((size_t)(h * 2 + (cb >> 3)) * Npad + gr) * 8 + (cb & 7)] = v;
            if (cb == 0) {
                alpha_s[gr * H + h] = ps;
                alpha_d[gr * H + h] = pd;
            }
        }
    }
}

// ---------------- fused per-node max + per-edge weights ----------------
__global__ __launch_bounds__(256) void attn_kernel(const float4* __restrict__ as4,
                                                   const float4* __restrict__ ad4,
                                                   const int* __restrict__ row_off,
                                                   const int* __restrict__ csr_src,
                                                   uint2* __restrict__ pk, int N, int M) {
    int n = blockIdx.x * 4 + (threadIdx.x >> 6);
    if (n >= N) return;
    int l = threadIdx.x & 63;
    int beg = row_off[n], end = row_off[n + 1];
    float4 mx = make_float4(-1e30f, -1e30f, -1e30f, -1e30f);
    for (int e = beg + l; e < end; e += 64) {
        float4 a = as4[csr_src[e]];
        mx.x = fmaxf(mx.x, a.x); mx.y = fmaxf(mx.y, a.y);
        mx.z = fmaxf(mx.z, a.z); mx.w = fmaxf(mx.w, a.w);
    }
    #pragma unroll
    for (int off = 32; off >= 1; off >>= 1) {
        mx.x = fmaxf(mx.x, __shfl_xor(mx.x, off));
        mx.y = fmaxf(mx.y, __shfl_xor(mx.y, off));
        mx.z = fmaxf(mx.z, __shfl_xor(mx.z, off));
        mx.w = fmaxf(mx.w, __shfl_xor(mx.w, off));
    }
    float4 d = ad4[n];
    float4 m;
    m.x = leaky(mx.x + d.x); m.y = leaky(mx.y + d.y);
    m.z = leaky(mx.z + d.z); m.w = leaky(mx.w + d.w);
    for (int e = beg + l; e < end; e += 64) {
        int s = csr_src[e];
        float4 a = as4[s];
        unsigned int su = (unsigned int)s;
        pk[e]                 = make_uint2(su, __float_as_uint(__expf(leaky(a.x + d.x) - m.x)));
        pk[(size_t)M + e]     = make_uint2(su, __float_as_uint(__expf(leaky(a.y + d.y) - m.y)));
        pk[(size_t)2 * M + e] = make_uint2(su, __float_as_uint(__expf(leaky(a.z + d.z) - m.z)));
        pk[(size_t)3 * M + e] = make_uint2(su, __float_as_uint(__expf(leaky(a.w + d.w) - m.w)));
    }
}

// ---------------- aggregation v8: one node per wave, 4 edge-slots x 16 lanes ----------------
// Wave-batch pk load (64 edges / 1 VMEM) + ds_bpermute slot redistribution;
// gather = dwordx2 per lane, 16 lanes span the 128B row -> 1 VMEM per 4 edges.
__global__ __launch_bounds__(256) void aggregate_v8(const unsigned short* __restrict__ xh_bf,
                                                    const uint2* __restrict__ pk,
                                                    const int* __restrict__ row_off,
                                                    unsigned short* __restrict__ hout,
                                                    int N, int Npad, int M) {
    int i = blockIdx.x;
    int slab = i & 7;
    int h = slab >> 1;
    int t = threadIdx.x;
    int wv = t >> 6;
    int lane = t & 63;
    int slot = lane >> 4;          // 0..3
    int l16 = lane & 15;
    int n = (i >> 3) * 4 + wv;
    if (n >= N) return;
    int beg = row_off[n], end = row_off[n + 1];

    i32x4 rx = make_rsrc(xh_bf + (size_t)slab * Npad * 64, (unsigned int)Npad * 128u);
    i32x4 rp = make_rsrc(pk + (size_t)h * M, (unsigned int)M * 8u);
    int ld8 = l16 << 3;
    int slot4 = slot << 2;

    float a0 = 0.f, a1 = 0.f, a2 = 0.f, a3 = 0.f, den = 0.f;

    for (int ebase = beg; ebase < end; ebase += 64) {
        // one pk batch: lane l <-> edge ebase+l
        i32x2 p = amd_buf_load_i32x2(rp, (ebase + lane) << 3, 0, 0);
        int nrem = end - ebase;
        int jmax = (nrem < 64 ? nrem + 7 : 71) >> 3;   // ceil(min(nrem,64)/8)
        for (int j = 0; j < jmax; ++j) {
            int addr = (j << 5) + slot4;               // source lane (8j+slot)*4
            int sx0 = __builtin_amdgcn_ds_bpermute(addr, p.x);
            int sy0 = __builtin_amdgcn_ds_bpermute(addr, p.y);
            int sx1 = __builtin_amdgcn_ds_bpermute(addr + 16, p.x);
            int sy1 = __builtin_amdgcn_ds_bpermute(addr + 16, p.y);
            i32x2 g0 = amd_buf_load_i32x2(rx, (sx0 << 7) + ld8, 0, 0);
            i32x2 g1 = amd_buf_load_i32x2(rx, (sx1 << 7) + ld8, 0, 0);
            int e0 = ebase + (j << 3) + slot;
            float w0 = (e0 < end) ? __uint_as_float((unsigned int)sy0) : 0.f;
            float w1 = (e0 + 4 < end) ? __uint_as_float((unsigned int)sy1) : 0.f;
            den += w0 + w1;
            a0 += w0 * bflo((unsigned int)g0.x); a1 += w0 * bfhi((unsigned int)g0.x);
            a2 += w0 * bflo((unsigned int)g0.y); a3 += w0 * bfhi((unsigned int)g0.y);
            a0 += w1 * bflo((unsigned int)g1.x); a1 += w1 * bfhi((unsigned int)g1.x);
            a2 += w1 * bflo((unsigned int)g1.y); a3 += w1 * bfhi((unsigned int)g1.y);
        }
    }

    // reduce across the 4 slots (lane bits 4 and 5)
    a0 += __shfl_xor(a0, 16); a1 += __shfl_xor(a1, 16);
    a2 += __shfl_xor(a2, 16); a3 += __shfl_xor(a3, 16);
    den += __shfl_xor(den, 16);
    a0 += __shfl_xor(a0, 32); a1 += __shfl_xor(a1, 32);
    a2 += __shfl_xor(a2, 32); a3 += __shfl_xor(a3, 32);
    den += __shfl_xor(den, 32);

    if (slot == 0) {
        float inv = 1.f / den;
        uint2 o;
        o.x = f2bf_bits(a0 * inv) | (f2bf_bits(a1 * inv) << 16);
        o.y = f2bf_bits(a2 * inv) | (f2bf_bits(a3 * inv) << 16);
        ((uint2*)hout)[((size_t)slab * Npad + n) * 16 + l16] = o;
    }
}

// ---------------- head mean + bias -> bf16 feats ----------------
__global__ void combine_kernel(const unsigned short* __restrict__ hout,
                               const float* __restrict__ bias,
                               unsigned short* __restrict__ featsbf, int N, int Npad) {
    int i = blockIdx.x * blockDim.x + threadIdx.x;   // dword index over [N][64]
    if (i >= N * 64) return;
    int n = i >> 6, c2 = i & 63;
    int chalf = c2 >> 5, ld = c2 & 31;
    const unsigned int* hp = (const unsigned int*)hout;
    float lo = 0.f, hi = 0.f;
    #pragma unroll
    for (int h = 0; h < 4; ++h) {
        unsigned int v = hp[((size_t)(h * 2 + chalf) * Npad + n) * 32 + ld];
        lo += bflo(v); hi += bfhi(v);
    }
    lo = 0.25f * lo + bias[c2 * 2];
    hi = 0.25f * hi + bias[c2 * 2 + 1];
    ((unsigned int*)featsbf)[(size_t)n * 64 + c2] = f2bf_bits(lo) | (f2bf_bits(hi) << 16);
}

// ---------------- pairwise scorer (bf16 feats, packed coords) ----------------
__global__ __launch_bounds__(256) void pair_kernel(const unsigned short* __restrict__ featsbf,
                                                   const float2* __restrict__ coords,
                                                   const int* __restrict__ idx, int P,
                                                   const float* __restrict__ fc_w,
                                                   const float* __restrict__ fc_b,
                                                   float* __restrict__ out) {
    int p = blockIdx.x * 4 + (threadIdx.x >> 6);
    int l = threadIdx.x & 63;
    if (p >= P) return;
    int i0 = idx[p], i1 = idx[P + p];
    unsigned int a = ((const unsigned int*)featsbf)[(size_t)i0 * 64 + l];
    unsigned int b = ((const unsigned int*)featsbf)[(size_t)i1 * 64 + l];
    float s = bflo(a) * bflo(b) + bfhi(a) * bfhi(b);
    #pragma unroll
    for (int off = 32; off >= 1; off >>= 1) s += __shfl_xor(s, off);
    if (l == 0) {
        float2 c0 = coords[i0], c1 = coords[i1];
        float dx = c0.x - c1.x;
        float dy = c0.y - c1.y;
        float pe = dx * dx + dy * dy;
        out[p] = fc_w[0] * s + fc_w[1] * pe + fc_b[0];
    }
}

extern "C" void kernel_launch(void* const* d_in, const int* in_sizes, int n_in,
                              void* d_out, int out_size, void* d_ws, size_t ws_size,
                              hipStream_t stream) {
    const float* x   = (const float*)d_in[0];
    const int*   ei  = (const int*)d_in[1];
    const int*   idx = (const int*)d_in[2];
    const float* W1  = (const float*)d_in[3];
    const float* as1 = (const float*)d_in[4];
    const float* ad1 = (const float*)d_in[5];
    const float* b1  = (const float*)d_in[6];
    const float* W2  = (const float*)d_in[7];
    const float* as2 = (const float*)d_in[8];
    const float* ad2 = (const float*)d_in[9];
    const float* b2  = (const float*)d_in[10];
    const float* fcw = (const float*)d_in[11];
    const float* fcb = (const float*)d_in[12];
    float* out = (float*)d_out;

    const int N = in_sizes[0] / 130;
    const int E = in_sizes[1] / 2;
    const int P = in_sizes[2] / 2;
    const int M = E + N;
    const int Npad = (N + 127) & ~127;

    char* ws = (char*)d_ws;
    size_t off = 0;
    auto alloc = [&](size_t bytes) -> void* {
        void* p = ws + off;
        off += (bytes + 255) & ~(size_t)255;
        return p;
    };
    unsigned short* xh_bf   = (unsigned short*)alloc((size_t)Npad * FOUT * 2);
    unsigned short* hout    = (unsigned short*)alloc((size_t)Npad * FOUT * 2);
    unsigned short* xA      = (unsigned short*)alloc((size_t)Npad * C * 2);
    unsigned short* featsbf = (unsigned short*)alloc((size_t)Npad * C * 2);
    unsigned short* Wt1     = (unsigned short*)alloc((size_t)128 * FOUT * 2);
    unsigned short* Wt2     = (unsigned short*)alloc((size_t)128 * FOUT * 2);
    float*          alpha_s = (float*)alloc((size_t)N * H * 4);
    float*          alpha_d = (float*)alloc((size_t)N * H * 4);
    float2*         coords  = (float2*)alloc((size_t)N * 8);
    uint2*          pk      = (uint2*)alloc((size_t)M * H * 8);
    int*            row_off = (int*)alloc((size_t)(N + 1) * 4);
    int*            cursor  = (int*)alloc((size_t)N * 4);
    int*            counts  = (int*)alloc((size_t)N * 4);
    int*            csr_src = (int*)alloc((size_t)M * 4);

    // CSR by dst (shared across both layers)
    zero_i32<<<(N + 255) / 256, 256, 0, stream>>>(counts, N);
    hist_kernel<<<(M + 255) / 256, 256, 0, stream>>>(ei, E, N, counts);
    scan_kernel<<<1, 256, 0, stream>>>(counts, row_off, cursor, N);
    scatter_kernel<<<(M + 255) / 256, 256, 0, stream>>>(ei, E, N, cursor, csr_src);

    // input conversions
    convert_x<<<(Npad * (C / 4) + 255) / 256, 256, 0, stream>>>(x, xA, featsbf, coords, N, Npad);
    convert_w<<<(128 * FOUT + 255) / 256, 256, 0, stream>>>(W1, W2, Wt1, Wt2);

    dim3 ggrid(H, Npad / 128);
    int aggGrid = ((N + 3) / 4) * 8;
    int cmbGrid = (N * 64 + 255) / 256;

    // layer 1
    gemm_direct<<<ggrid, 256, 0, stream>>>(xA, Wt1, as1, ad1, xh_bf, alpha_s, alpha_d, N, Npad);
    attn_kernel<<<(N + 3) / 4, 256, 0, stream>>>((const float4*)alpha_s, (const float4*)alpha_d,
                                                 row_off, csr_src, pk, N, M);
    aggregate_v8<<<aggGrid, 256, 0, stream>>>(xh_bf, pk, row_off, hout, N, Npad, M);
    combine_kernel<<<cmbGrid, 256, 0, stream>>>(hout, b1, featsbf, N, Npad);

    // layer 2
    gemm_direct<<<ggrid, 256, 0, stream>>>(featsbf, Wt2, as2, ad2, xh_bf, alpha_s, alpha_d, N, Npad);
    attn_kernel<<<(N + 3) / 4, 256, 0, stream>>>((const float4*)alpha_s, (const float4*)alpha_d,
                                                 row_off, csr_src, pk, N, M);
    aggregate_v8<<<aggGrid, 256, 0, stream>>>(xh_bf, pk, row_off, hout, N, Npad, M);
    combine_kernel<<<cmbGrid, 256, 0, stream>>>(hout, b2, featsbf, N, Npad);

    // pairwise output
    pair_kernel<<<(P + 3) / 4, 256, 0, stream>>>(featsbf, coords, idx, P, fcw, fcb, out);
}

// Round 9
// 285.342 us; speedup vs baseline: 1.0415x; 1.0045x over previous
//
#include <hip/hip_runtime.h>
#include <hip/hip_fp16.h>

#define H 4
#define C 128
#define FOUT 512

typedef __attribute__((ext_vector_type(8))) short s16x8;
typedef __attribute__((ext_vector_type(4))) float f32x4;
typedef __attribute__((ext_vector_type(4))) int i32x4;
typedef __attribute__((ext_vector_type(2))) int i32x2;

// CK-style raw buffer-load intrinsics (32-bit voffset addressing)
__device__ int amd_buf_load_i32(i32x4 rsrc, int voffset, int soffset, int aux) __asm("llvm.amdgcn.raw.buffer.load.i32");
__device__ i32x2 amd_buf_load_i32x2(i32x4 rsrc, int voffset, int soffset, int aux) __asm("llvm.amdgcn.raw.buffer.load.v2i32");

__device__ __forceinline__ i32x4 make_rsrc(const void* p, unsigned int bytes) {
    i32x4 r;
    r.x = (int)(unsigned int)(unsigned long long)p;
    r.y = (int)(unsigned int)(((unsigned long long)p) >> 32);
    r.z = (int)bytes;          // num_records (stride==0 -> bytes); OOB load returns 0
    r.w = 0x00020000;          // raw untyped dword access
    return r;
}

__device__ __forceinline__ unsigned int f2bf_bits(float f) {
    unsigned int u = __float_as_uint(f);
    u += 0x7fffu + ((u >> 16) & 1u);
    return u >> 16;
}
__device__ __forceinline__ float bflo(unsigned int u) { return __uint_as_float(u << 16); }
__device__ __forceinline__ float bfhi(unsigned int u) { return __uint_as_float(u & 0xffff0000u); }
__device__ __forceinline__ float leaky(float x) { return (x >= 0.f) ? x : 0.2f * x; }
__device__ __forceinline__ __half2 u2h2(unsigned int u) {
    union { unsigned int u; __half2 h; } c; c.u = u; return c.h;
}
__device__ __forceinline__ unsigned int pkrtz_bits(float a, float b) {
    auto v = __builtin_amdgcn_cvt_pkrtz(a, b);
    union { decltype(v) h; unsigned int u; } c; c.h = v; return c.u;
}

// ---------------- CSR build ----------------
__global__ void zero_i32(int* __restrict__ p, int n) {
    int i = blockIdx.x * blockDim.x + threadIdx.x;
    if (i < n) p[i] = 0;
}

__global__ void hist_kernel(const int* __restrict__ ei, int E, int N, int* __restrict__ counts) {
    int e = blockIdx.x * blockDim.x + threadIdx.x;
    int M = E + N;
    if (e >= M) return;
    int d = (e < E) ? ei[E + e] : (e - E);
    atomicAdd(&counts[d], 1);
}

__global__ __launch_bounds__(256) void scan_kernel(const int* __restrict__ counts,
                                                   int* __restrict__ row_off,
                                                   int* __restrict__ cursor, int N) {
    __shared__ int part[256];
    int t = threadIdx.x;
    int chunk = (N + 255) >> 8;
    int b = t * chunk; if (b > N) b = N;
    int e = b + chunk; if (e > N) e = N;
    int s = 0;
    for (int i = b; i < e; ++i) s += counts[i];
    part[t] = s;
    __syncthreads();
    for (int off = 1; off < 256; off <<= 1) {
        int v = (t >= off) ? part[t - off] : 0;
        __syncthreads();
        part[t] += v;
        __syncthreads();
    }
    int run = (t == 0) ? 0 : part[t - 1];
    for (int i = b; i < e; ++i) { row_off[i] = run; cursor[i] = run; run += counts[i]; }
    if (t == 255) row_off[N] = part[255];
}

__global__ void scatter_kernel(const int* __restrict__ ei, int E, int N,
                               int* __restrict__ cursor, int* __restrict__ csr_src) {
    int e = blockIdx.x * blockDim.x + threadIdx.x;
    int M = E + N;
    if (e >= M) return;
    int s = (e < E) ? ei[e] : (e - E);
    int d = (e < E) ? ei[E + e] : (e - E);
    int pos = atomicAdd(&cursor[d], 1);
    csr_src[pos] = s;
}

// ---------------- input conversions ----------------
__global__ void convert_x(const float* __restrict__ x, unsigned short* __restrict__ xA,
                          unsigned short* __restrict__ featsbf, float2* __restrict__ coords,
                          int N, int Npad) {
    int i = blockIdx.x * blockDim.x + threadIdx.x;  // one 4-channel group per thread
    int total = Npad * (C / 4);
    if (i >= total) return;
    int row = i >> 5;
    int c4 = (i & 31) * 4;
    ushort4 o;
    if (row < N) {
        const float* p = x + (size_t)row * 130 + 2 + c4;
        float2 v0 = *(const float2*)p;
        float2 v1 = *(const float2*)(p + 2);
        o.x = (unsigned short)f2bf_bits(v0.x);
        o.y = (unsigned short)f2bf_bits(v0.y);
        o.z = (unsigned short)f2bf_bits(v1.x);
        o.w = (unsigned short)f2bf_bits(v1.y);
        if ((i & 31) == 0) coords[row] = *(const float2*)&x[(size_t)row * 130];
    } else {
        o = make_ushort4(0, 0, 0, 0);
        *(ushort4*)&featsbf[(size_t)row * C + c4] = o;   // zero pad rows of layer-2 input
    }
    *(ushort4*)&xA[(size_t)row * C + c4] = o;
}

__global__ void convert_w(const float* __restrict__ W1, const float* __restrict__ W2,
                          unsigned short* __restrict__ Wt1, unsigned short* __restrict__ Wt2) {
    int i = blockIdx.x * blockDim.x + threadIdx.x;
    if (i >= 128 * 512) return;
    int c = i >> 7, k = i & 127;
    Wt1[i] = (unsigned short)f2bf_bits(W1[(size_t)k * FOUT + c]);
    Wt2[i] = (unsigned short)f2bf_bits(W2[(size_t)k * FOUT + c]);
}

// ---------------- MFMA GEMM v3: swapped operands, no C-transpose LDS ----------------
// acc[i][j] = mfma(Bfrag, Afrag): lane holds 4 CONSECUTIVE output cols per acc reg ->
// direct f16-packed dwordx2 stores to slab layout [h*2+wc][Npad][64]. Alpha from fp32 acc.
__global__ __launch_bounds__(256) void gemm_v3(const unsigned short* __restrict__ A,
                                               const unsigned short* __restrict__ Bt,
                                               const float* __restrict__ a_src,
                                               const float* __restrict__ a_dst,
                                               unsigned short* __restrict__ Xh,
                                               float* __restrict__ alpha_s,
                                               float* __restrict__ alpha_d,
                                               int Nrows, int Npad) {
    __shared__ float albuf[2][4][16][2][2];   // [wr][i][l16][wc][ps/pd]
    int t = threadIdx.x;
    int lane = t & 63;
    int wv = t >> 6;
    int wr = wv >> 1, wc = wv & 1;
    int lr = lane & 15;
    int ksel = lane >> 4;
    int h = blockIdx.x;
    int r0 = blockIdx.y * 128;

    f32x4 acc[4][4];
    #pragma unroll
    for (int i = 0; i < 4; ++i)
        #pragma unroll
        for (int j = 0; j < 4; ++j) acc[i][j] = (f32x4){0.f, 0.f, 0.f, 0.f};

    const s16x8* Ab = (const s16x8*)(A + (size_t)(r0 + wr * 64 + lr) * C);
    const s16x8* Bb = (const s16x8*)(Bt + (size_t)(h * 128 + wc * 64 + lr) * C);

    #pragma unroll
    for (int ks = 0; ks < 4; ++ks) {
        int cb = ks * 4 + ksel;
        s16x8 af[4], bf[4];
        #pragma unroll
        for (int i = 0; i < 4; ++i) {
            af[i] = Ab[(size_t)(i * 16) * 16 + cb];
            bf[i] = Bb[(size_t)(i * 16) * 16 + cb];
        }
        #pragma unroll
        for (int i = 0; i < 4; ++i)
            #pragma unroll
            for (int j = 0; j < 4; ++j)
                acc[i][j] = __builtin_amdgcn_mfma_f32_16x16x32_bf16(bf[j], af[i], acc[i][j], 0, 0, 0);
    }

    // alpha coefficients for this lane's 16 cols (4 per j)
    float4 avj[4], dvj[4];
    #pragma unroll
    for (int j = 0; j < 4; ++j) {
        int cc = h * C + wc * 64 + j * 16 + ksel * 4;
        avj[j] = *(const float4*)&a_src[cc];
        dvj[j] = *(const float4*)&a_dst[cc];
    }

    // stores + alpha partials
    unsigned short* slabp = Xh + (size_t)(h * 2 + wc) * Npad * 64;
    float ps[4] = {0.f, 0.f, 0.f, 0.f}, pd[4] = {0.f, 0.f, 0.f, 0.f};
    #pragma unroll
    for (int i = 0; i < 4; ++i) {
        int gr = r0 + wr * 64 + i * 16 + lr;
        #pragma unroll
        for (int j = 0; j < 4; ++j) {
            f32x4 a4 = acc[i][j];
            ps[i] += a4[0] * avj[j].x + a4[1] * avj[j].y + a4[2] * avj[j].z + a4[3] * avj[j].w;
            pd[i] += a4[0] * dvj[j].x + a4[1] * dvj[j].y + a4[2] * dvj[j].z + a4[3] * dvj[j].w;
            uint2 o;
            o.x = pkrtz_bits(a4[0], a4[1]);
            o.y = pkrtz_bits(a4[2], a4[3]);
            *(uint2*)(slabp + (size_t)gr * 64 + j * 16 + ksel * 4) = o;
        }
        ps[i] += __shfl_xor(ps[i], 16); ps[i] += __shfl_xor(ps[i], 32);
        pd[i] += __shfl_xor(pd[i], 16); pd[i] += __shfl_xor(pd[i], 32);
    }
    if (lane < 16) {
        #pragma unroll
        for (int i = 0; i < 4; ++i) {
            albuf[wr][i][lane][wc][0] = ps[i];
            albuf[wr][i][lane][wc][1] = pd[i];
        }
    }
    __syncthreads();

    // combine wc halves: 128 rows x {ps,pd}
    int rid = t >> 1, which = t & 1;
    int wr2 = rid >> 6, rem = rid & 63, i2 = rem >> 4, l2 = rem & 15;
    float v = albuf[wr2][i2][l2][0][which] + albuf[wr2][i2][l2][1][which];
    int gr = r0 + wr2 * 64 + i2 * 16 + l2;
    if (gr < Nrows) {
        if (which) alpha_d[gr * H + h] = v;
        else       alpha_s[gr * H + h] = v;
    }
}

// ---------------- fused per-node max + per-edge packed weights ----------------
// pk[h][e] = (f16(w) << 16) | src   (src < 65536)
__global__ __launch_bounds__(256) void attn_kernel(const float4* __restrict__ as4,
                                                   const float4* __restrict__ ad4,
                                                   const int* __restrict__ row_off,
                                                   const int* __restrict__ csr_src,
                                                   unsigned int* __restrict__ pk, int N, int M) {
    int n = blockIdx.x * 4 + (threadIdx.x >> 6);
    if (n >= N) return;
    int l = threadIdx.x & 63;
    int beg = row_off[n], end = row_off[n + 1];
    float4 mx = make_float4(-1e30f, -1e30f, -1e30f, -1e30f);
    for (int e = beg + l; e < end; e += 64) {
        float4 a = as4[csr_src[e]];
        mx.x = fmaxf(mx.x, a.x); mx.y = fmaxf(mx.y, a.y);
        mx.z = fmaxf(mx.z, a.z); mx.w = fmaxf(mx.w, a.w);
    }
    #pragma unroll
    for (int off = 32; off >= 1; off >>= 1) {
        mx.x = fmaxf(mx.x, __shfl_xor(mx.x, off));
        mx.y = fmaxf(mx.y, __shfl_xor(mx.y, off));
        mx.z = fmaxf(mx.z, __shfl_xor(mx.z, off));
        mx.w = fmaxf(mx.w, __shfl_xor(mx.w, off));
    }
    float4 d = ad4[n];
    float4 m;
    m.x = leaky(mx.x + d.x); m.y = leaky(mx.y + d.y);
    m.z = leaky(mx.z + d.z); m.w = leaky(mx.w + d.w);
    for (int e = beg + l; e < end; e += 64) {
        int s = csr_src[e];
        float4 a = as4[s];
        unsigned int su = (unsigned int)s;
        unsigned int w0 = (unsigned int)__half_as_ushort(__float2half(__expf(leaky(a.x + d.x) - m.x)));
        unsigned int w1 = (unsigned int)__half_as_ushort(__float2half(__expf(leaky(a.y + d.y) - m.y)));
        unsigned int w2 = (unsigned int)__half_as_ushort(__float2half(__expf(leaky(a.z + d.z) - m.z)));
        unsigned int w3 = (unsigned int)__half_as_ushort(__float2half(__expf(leaky(a.w + d.w) - m.w)));
        pk[e]                 = (w0 << 16) | su;
        pk[(size_t)M + e]     = (w1 << 16) | su;
        pk[(size_t)2 * M + e] = (w2 << 16) | su;
        pk[(size_t)3 * M + e] = (w3 << 16) | su;
    }
}

// ---------------- aggregation v9: f16 gathers, packed pk, pk_fma accumulation ----------------
__global__ __launch_bounds__(256) void aggregate_v9(const unsigned short* __restrict__ xh,
                                                    const unsigned int* __restrict__ pk,
                                                    const int* __restrict__ row_off,
                                                    unsigned short* __restrict__ hout,
                                                    int N, int Npad, int M) {
    int i = blockIdx.x;
    int slab = i & 7;
    int h = slab >> 1;
    int t = threadIdx.x;
    int wv = t >> 6;
    int lane = t & 63;
    int slot = lane >> 4;
    int l16 = lane & 15;
    int n = (i >> 3) * 4 + wv;
    if (n >= N) return;
    int beg = row_off[n], end = row_off[n + 1];

    i32x4 rx = make_rsrc(xh + (size_t)slab * Npad * 64, (unsigned int)Npad * 128u);
    i32x4 rp = make_rsrc(pk + (size_t)h * M, (unsigned int)M * 4u);
    int ld8 = l16 << 3;
    int slot4 = slot << 2;

    __half2 acc01 = u2h2(0), acc23 = u2h2(0), den2 = u2h2(0);

    for (int ebase = beg; ebase < end; ebase += 64) {
        int p = amd_buf_load_i32(rp, (ebase + lane) << 2, 0, 0);
        int nrem = end - ebase;
        int jmax = ((nrem < 64 ? nrem : 64) + 7) >> 3;
        for (int j = 0; j < jmax; ++j) {
            int addr = (j << 5) + slot4;
            int sp0 = __builtin_amdgcn_ds_bpermute(addr, p);
            int sp1 = __builtin_amdgcn_ds_bpermute(addr + 16, p);
            int e0 = ebase + (j << 3) + slot;
            i32x2 ga = amd_buf_load_i32x2(rx, ((sp0 & 0xffff) << 7) + ld8, 0, 0);
            i32x2 gb = amd_buf_load_i32x2(rx, ((sp1 & 0xffff) << 7) + ld8, 0, 0);
            unsigned int wa2 = __builtin_amdgcn_perm(sp0, sp0, 0x03020302);
            unsigned int wb2 = __builtin_amdgcn_perm(sp1, sp1, 0x03020302);
            if (e0 >= end) wa2 = 0u;
            if (e0 + 4 >= end) wb2 = 0u;
            __half2 wha = u2h2(wa2), whb = u2h2(wb2);
            acc01 = __hfma2(wha, u2h2((unsigned int)ga.x), acc01);
            acc23 = __hfma2(wha, u2h2((unsigned int)ga.y), acc23);
            acc01 = __hfma2(whb, u2h2((unsigned int)gb.x), acc01);
            acc23 = __hfma2(whb, u2h2((unsigned int)gb.y), acc23);
            den2 = __hadd2(den2, wha);
            den2 = __hadd2(den2, whb);
        }
    }

    float2 f01 = __half22float2(acc01);
    float2 f23 = __half22float2(acc23);
    float dd = __half2float(__low2half(den2));

    f01.x += __shfl_xor(f01.x, 16); f01.y += __shfl_xor(f01.y, 16);
    f23.x += __shfl_xor(f23.x, 16); f23.y += __shfl_xor(f23.y, 16);
    dd += __shfl_xor(dd, 16);
    f01.x += __shfl_xor(f01.x, 32); f01.y += __shfl_xor(f01.y, 32);
    f23.x += __shfl_xor(f23.x, 32); f23.y += __shfl_xor(f23.y, 32);
    dd += __shfl_xor(dd, 32);

    if (slot == 0) {
        float inv = 1.f / dd;
        uint2 o;
        o.x = f2bf_bits(f01.x * inv) | (f2bf_bits(f01.y * inv) << 16);
        o.y = f2bf_bits(f23.x * inv) | (f2bf_bits(f23.y * inv) << 16);
        ((uint2*)hout)[((size_t)slab * Npad + n) * 16 + l16] = o;
    }
}

// ---------------- head mean + bias -> bf16 feats ----------------
__global__ void combine_kernel(const unsigned short* __restrict__ hout,
                               const float* __restrict__ bias,
                               unsigned short* __restrict__ featsbf, int N, int Npad) {
    int i = blockIdx.x * blockDim.x + threadIdx.x;   // dword index over [N][64]
    if (i >= N * 64) return;
    int n = i >> 6, c2 = i & 63;
    int chalf = c2 >> 5, ld = c2 & 31;
    const unsigned int* hp = (const unsigned int*)hout;
    float lo = 0.f, hi = 0.f;
    #pragma unroll
    for (int h = 0; h < 4; ++h) {
        unsigned int v = hp[((size_t)(h * 2 + chalf) * Npad + n) * 32 + ld];
        lo += bflo(v); hi += bfhi(v);
    }
    lo = 0.25f * lo + bias[c2 * 2];
    hi = 0.25f * hi + bias[c2 * 2 + 1];
    ((unsigned int*)featsbf)[(size_t)n * 64 + c2] = f2bf_bits(lo) | (f2bf_bits(hi) << 16);
}

// ---------------- pairwise scorer (bf16 feats, packed coords) ----------------
__global__ __launch_bounds__(256) void pair_kernel(const unsigned short* __restrict__ featsbf,
                                                   const float2* __restrict__ coords,
                                                   const int* __restrict__ idx, int P,
                                                   const float* __restrict__ fc_w,
                                                   const float* __restrict__ fc_b,
                                                   float* __restrict__ out) {
    int p = blockIdx.x * 4 + (threadIdx.x >> 6);
    int l = threadIdx.x & 63;
    if (p >= P) return;
    int i0 = idx[p], i1 = idx[P + p];
    unsigned int a = ((const unsigned int*)featsbf)[(size_t)i0 * 64 + l];
    unsigned int b = ((const unsigned int*)featsbf)[(size_t)i1 * 64 + l];
    float s = bflo(a) * bflo(b) + bfhi(a) * bfhi(b);
    #pragma unroll
    for (int off = 32; off >= 1; off >>= 1) s += __shfl_xor(s, off);
    if (l == 0) {
        float2 c0 = coords[i0], c1 = coords[i1];
        float dx = c0.x - c1.x;
        float dy = c0.y - c1.y;
        float pe = dx * dx + dy * dy;
        out[p] = fc_w[0] * s + fc_w[1] * pe + fc_b[0];
    }
}

extern "C" void kernel_launch(void* const* d_in, const int* in_sizes, int n_in,
                              void* d_out, int out_size, void* d_ws, size_t ws_size,
                              hipStream_t stream) {
    const float* x   = (const float*)d_in[0];
    const int*   ei  = (const int*)d_in[1];
    const int*   idx = (const int*)d_in[2];
    const float* W1  = (const float*)d_in[3];
    const float* as1 = (const float*)d_in[4];
    const float* ad1 = (const float*)d_in[5];
    const float* b1  = (const float*)d_in[6];
    const float* W2  = (const float*)d_in[7];
    const float* as2 = (const float*)d_in[8];
    const float* ad2 = (const float*)d_in[9];
    const float* b2  = (const float*)d_in[10];
    const float* fcw = (const float*)d_in[11];
    const float* fcb = (const float*)d_in[12];
    float* out = (float*)d_out;

    const int N = in_sizes[0] / 130;
    const int E = in_sizes[1] / 2;
    const int P = in_sizes[2] / 2;
    const int M = E + N;
    const int Npad = (N + 127) & ~127;

    char* ws = (char*)d_ws;
    size_t off = 0;
    auto alloc = [&](size_t bytes) -> void* {
        void* p = ws + off;
        off += (bytes + 255) & ~(size_t)255;
        return p;
    };
    unsigned short* xh_f16  = (unsigned short*)alloc((size_t)Npad * FOUT * 2);
    unsigned short* hout    = (unsigned short*)alloc((size_t)Npad * FOUT * 2);
    unsigned short* xA      = (unsigned short*)alloc((size_t)Npad * C * 2);
    unsigned short* featsbf = (unsigned short*)alloc((size_t)Npad * C * 2);
    unsigned short* Wt1     = (unsigned short*)alloc((size_t)128 * FOUT * 2);
    unsigned short* Wt2     = (unsigned short*)alloc((size_t)128 * FOUT * 2);
    float*          alpha_s = (float*)alloc((size_t)N * H * 4);
    float*          alpha_d = (float*)alloc((size_t)N * H * 4);
    float2*         coords  = (float2*)alloc((size_t)N * 8);
    unsigned int*   pk      = (unsigned int*)alloc((size_t)M * H * 4);
    int*            row_off = (int*)alloc((size_t)(N + 1) * 4);
    int*            cursor  = (int*)alloc((size_t)N * 4);
    int*            counts  = (int*)alloc((size_t)N * 4);
    int*            csr_src = (int*)alloc((size_t)M * 4);

    // CSR by dst (shared across both layers)
    zero_i32<<<(N + 255) / 256, 256, 0, stream>>>(counts, N);
    hist_kernel<<<(M + 255) / 256, 256, 0, stream>>>(ei, E, N, counts);
    scan_kernel<<<1, 256, 0, stream>>>(counts, row_off, cursor, N);
    scatter_kernel<<<(M + 255) / 256, 256, 0, stream>>>(ei, E, N, cursor, csr_src);

    // input conversions
    convert_x<<<(Npad * (C / 4) + 255) / 256, 256, 0, stream>>>(x, xA, featsbf, coords, N, Npad);
    convert_w<<<(128 * FOUT + 255) / 256, 256, 0, stream>>>(W1, W2, Wt1, Wt2);

    dim3 ggrid(H, Npad / 128);
    int aggGrid = ((N + 3) / 4) * 8;
    int cmbGrid = (N * 64 + 255) / 256;

    // layer 1
    gemm_v3<<<ggrid, 256, 0, stream>>>(xA, Wt1, as1, ad1, xh_f16, alpha_s, alpha_d, N, Npad);
    attn_kernel<<<(N + 3) / 4, 256, 0, stream>>>((const float4*)alpha_s, (const float4*)alpha_d,
                                                 row_off, csr_src, pk, N, M);
    aggregate_v9<<<aggGrid, 256, 0, stream>>>(xh_f16, pk, row_off, hout, N, Npad, M);
    combine_kernel<<<cmbGrid, 256, 0, stream>>>(hout, b1, featsbf, N, Npad);

    // layer 2
    gemm_v3<<<ggrid, 256, 0, stream>>>(featsbf, Wt2, as2, ad2, xh_f16, alpha_s, alpha_d, N, Npad);
    attn_kernel<<<(N + 3) / 4, 256, 0, stream>>>((const float4*)alpha_s, (const float4*)alpha_d,
                                                 row_off, csr_src, pk, N, M);
    aggregate_v9<<<aggGrid, 256, 0, stream>>>(xh_f16, pk, row_off, hout, N, Npad, M);
    combine_kernel<<<cmbGrid, 256, 0, stream>>>(hout, b2, featsbf, N, Npad);

    // pairwise output
    pair_kernel<<<(P + 3) / 4, 256, 0, stream>>>(featsbf, coords, idx, P, fcw, fcb, out);
}

// Round 10
// 271.008 us; speedup vs baseline: 1.0966x; 1.0529x over previous
//
#include <hip/hip_runtime.h>
#include <hip/hip_fp16.h>

#define H 4
#define C 128
#define FOUT 512

typedef __attribute__((ext_vector_type(8))) short s16x8;
typedef __attribute__((ext_vector_type(4))) float f32x4;
typedef __attribute__((ext_vector_type(4))) int i32x4;
typedef __attribute__((ext_vector_type(2))) int i32x2;

// CK-style raw buffer-load intrinsics (32-bit voffset addressing)
__device__ int amd_buf_load_i32(i32x4 rsrc, int voffset, int soffset, int aux) __asm("llvm.amdgcn.raw.buffer.load.i32");
__device__ i32x2 amd_buf_load_i32x2(i32x4 rsrc, int voffset, int soffset, int aux) __asm("llvm.amdgcn.raw.buffer.load.v2i32");
__device__ i32x4 amd_buf_load_i32x4(i32x4 rsrc, int voffset, int soffset, int aux) __asm("llvm.amdgcn.raw.buffer.load.v4i32");

__device__ __forceinline__ i32x4 make_rsrc(const void* p, unsigned int bytes) {
    i32x4 r;
    r.x = (int)(unsigned int)(unsigned long long)p;
    r.y = (int)(unsigned int)(((unsigned long long)p) >> 32);
    r.z = (int)bytes;          // num_records; OOB load returns 0
    r.w = 0x00020000;          // raw untyped dword access
    return r;
}

__device__ __forceinline__ unsigned int f2bf_bits(float f) {
    unsigned int u = __float_as_uint(f);
    u += 0x7fffu + ((u >> 16) & 1u);
    return u >> 16;
}
// pack two f32 bit-patterns into one dword of 2 RNE bf16
__device__ __forceinline__ unsigned int pack2bf(unsigned int u0, unsigned int u1) {
    unsigned int r0 = (u0 + 0x7fffu + ((u0 >> 16) & 1u)) >> 16;
    unsigned int r1 = (u1 + 0x7fffu + ((u1 >> 16) & 1u)) & 0xffff0000u;
    return r0 | r1;
}
__device__ __forceinline__ float bflo(unsigned int u) { return __uint_as_float(u << 16); }
__device__ __forceinline__ float bfhi(unsigned int u) { return __uint_as_float(u & 0xffff0000u); }
__device__ __forceinline__ float leaky(float x) { return (x >= 0.f) ? x : 0.2f * x; }
__device__ __forceinline__ __half2 u2h2(unsigned int u) {
    union { unsigned int u; __half2 h; } c; c.u = u; return c.h;
}
__device__ __forceinline__ unsigned int h22u(__half2 h) {
    union { __half2 h; unsigned int u; } c; c.h = h; return c.u;
}
__device__ __forceinline__ unsigned int pkrtz_bits(float a, float b) {
    auto v = __builtin_amdgcn_cvt_pkrtz(a, b);
    union { decltype(v) h; unsigned int u; } c; c.h = v; return c.u;
}

// ---------------- prep: zero counts + convert weights ----------------
__global__ void prep_kernel(const float* __restrict__ W1, const float* __restrict__ W2,
                            unsigned short* __restrict__ Wt1, unsigned short* __restrict__ Wt2,
                            int* __restrict__ counts, int N) {
    int i = blockIdx.x * blockDim.x + threadIdx.x;
    if (i < N) counts[i] = 0;
    if (i < 128 * 512) {
        int c = i >> 7, k = i & 127;
        Wt1[i] = (unsigned short)f2bf_bits(W1[(size_t)k * FOUT + c]);
        Wt2[i] = (unsigned short)f2bf_bits(W2[(size_t)k * FOUT + c]);
    }
}

// ---------------- CSR build ----------------
__global__ void hist_kernel(const int* __restrict__ ei, int E, int N, int* __restrict__ counts) {
    int e = blockIdx.x * blockDim.x + threadIdx.x;
    int M = E + N;
    if (e >= M) return;
    int d = (e < E) ? ei[E + e] : (e - E);
    atomicAdd(&counts[d], 1);
}

__global__ __launch_bounds__(256) void scan_kernel(const int* __restrict__ counts,
                                                   int* __restrict__ row_off,
                                                   int* __restrict__ cursor, int N) {
    __shared__ int part[256];
    int t = threadIdx.x;
    int chunk = (N + 255) >> 8;
    int b = t * chunk; if (b > N) b = N;
    int e = b + chunk; if (e > N) e = N;
    int s = 0;
    for (int i = b; i < e; ++i) s += counts[i];
    part[t] = s;
    __syncthreads();
    for (int off = 1; off < 256; off <<= 1) {
        int v = (t >= off) ? part[t - off] : 0;
        __syncthreads();
        part[t] += v;
        __syncthreads();
    }
    int run = (t == 0) ? 0 : part[t - 1];
    for (int i = b; i < e; ++i) { row_off[i] = run; cursor[i] = run; run += counts[i]; }
    if (t == 255) row_off[N] = part[255];
}

__global__ void scatter_kernel(const int* __restrict__ ei, int E, int N,
                               int* __restrict__ cursor, int* __restrict__ csr_src) {
    int e = blockIdx.x * blockDim.x + threadIdx.x;
    int M = E + N;
    if (e >= M) return;
    int s = (e < E) ? ei[e] : (e - E);
    int d = (e < E) ? ei[E + e] : (e - E);
    int pos = atomicAdd(&cursor[d], 1);
    csr_src[pos] = s;
}

// ---------------- MFMA GEMM v4: buffer-load A (fused x conversion), swapped operands ----------------
// IS_X: A = x (fp32, row stride 520B, +8B col offset, OOB-zero pads); else A = featsbf (bf16, 256B rows).
template <bool IS_X>
__global__ __launch_bounds__(256) void gemm_v4(const void* __restrict__ Asrc, int Nrows,
                                               const unsigned short* __restrict__ Bt,
                                               const float* __restrict__ a_src,
                                               const float* __restrict__ a_dst,
                                               unsigned short* __restrict__ Xh,
                                               float* __restrict__ alpha_s,
                                               float* __restrict__ alpha_d,
                                               int Npad) {
    __shared__ float albuf[2][4][16][2][2];   // [wr][i][l16][wc][ps/pd]
    int t = threadIdx.x;
    int lane = t & 63;
    int wv = t >> 6;
    int wr = wv >> 1, wc = wv & 1;
    int lr = lane & 15;
    int ksel = lane >> 4;
    int h = blockIdx.x;
    int r0 = blockIdx.y * 128;

    i32x4 rA = make_rsrc(Asrc, IS_X ? (unsigned int)Nrows * 520u : (unsigned int)Nrows * 256u);

    f32x4 acc[4][4];
    #pragma unroll
    for (int i = 0; i < 4; ++i)
        #pragma unroll
        for (int j = 0; j < 4; ++j) acc[i][j] = (f32x4){0.f, 0.f, 0.f, 0.f};

    const s16x8* Bb = (const s16x8*)(Bt + (size_t)(h * 128 + wc * 64 + lr) * C);

    #pragma unroll
    for (int ks = 0; ks < 4; ++ks) {
        int cb = ks * 4 + ksel;
        s16x8 af[4], bf[4];
        #pragma unroll
        for (int i = 0; i < 4; ++i) {
            int gr = r0 + wr * 64 + i * 16 + lr;
            if constexpr (IS_X) {
                int base = gr * 520 + 8 + cb * 32;
                i32x2 u0 = amd_buf_load_i32x2(rA, base, 0, 0);
                i32x2 u1 = amd_buf_load_i32x2(rA, base + 8, 0, 0);
                i32x2 u2 = amd_buf_load_i32x2(rA, base + 16, 0, 0);
                i32x2 u3 = amd_buf_load_i32x2(rA, base + 24, 0, 0);
                i32x4 packed;
                packed.x = (int)pack2bf((unsigned int)u0.x, (unsigned int)u0.y);
                packed.y = (int)pack2bf((unsigned int)u1.x, (unsigned int)u1.y);
                packed.z = (int)pack2bf((unsigned int)u2.x, (unsigned int)u2.y);
                packed.w = (int)pack2bf((unsigned int)u3.x, (unsigned int)u3.y);
                af[i] = __builtin_bit_cast(s16x8, packed);
            } else {
                i32x4 v = amd_buf_load_i32x4(rA, gr * 256 + cb * 16, 0, 0);
                af[i] = __builtin_bit_cast(s16x8, v);
            }
            bf[i] = Bb[(size_t)(i * 16) * 16 + cb];
        }
        #pragma unroll
        for (int i = 0; i < 4; ++i)
            #pragma unroll
            for (int j = 0; j < 4; ++j)
                acc[i][j] = __builtin_amdgcn_mfma_f32_16x16x32_bf16(bf[j], af[i], acc[i][j], 0, 0, 0);
    }

    // alpha coefficients for this lane's 16 cols (4 per j)
    float4 avj[4], dvj[4];
    #pragma unroll
    for (int j = 0; j < 4; ++j) {
        int cc = h * C + wc * 64 + j * 16 + ksel * 4;
        avj[j] = *(const float4*)&a_src[cc];
        dvj[j] = *(const float4*)&a_dst[cc];
    }

    // stores (f16 slab layout) + alpha partials
    unsigned short* slabp = Xh + (size_t)(h * 2 + wc) * Npad * 64;
    float ps[4] = {0.f, 0.f, 0.f, 0.f}, pd[4] = {0.f, 0.f, 0.f, 0.f};
    #pragma unroll
    for (int i = 0; i < 4; ++i) {
        int gr = r0 + wr * 64 + i * 16 + lr;
        #pragma unroll
        for (int j = 0; j < 4; ++j) {
            f32x4 a4 = acc[i][j];
            ps[i] += a4[0] * avj[j].x + a4[1] * avj[j].y + a4[2] * avj[j].z + a4[3] * avj[j].w;
            pd[i] += a4[0] * dvj[j].x + a4[1] * dvj[j].y + a4[2] * dvj[j].z + a4[3] * dvj[j].w;
            uint2 o;
            o.x = pkrtz_bits(a4[0], a4[1]);
            o.y = pkrtz_bits(a4[2], a4[3]);
            *(uint2*)(slabp + (size_t)gr * 64 + j * 16 + ksel * 4) = o;
        }
        ps[i] += __shfl_xor(ps[i], 16); ps[i] += __shfl_xor(ps[i], 32);
        pd[i] += __shfl_xor(pd[i], 16); pd[i] += __shfl_xor(pd[i], 32);
    }
    if (lane < 16) {
        #pragma unroll
        for (int i = 0; i < 4; ++i) {
            albuf[wr][i][lane][wc][0] = ps[i];
            albuf[wr][i][lane][wc][1] = pd[i];
        }
    }
    __syncthreads();

    // combine wc halves: 128 rows x {ps,pd}
    int rid = t >> 1, which = t & 1;
    int wr2 = rid >> 6, rem = rid & 63, i2 = rem >> 4, l2 = rem & 15;
    float v = albuf[wr2][i2][l2][0][which] + albuf[wr2][i2][l2][1][which];
    int gr = r0 + wr2 * 64 + i2 * 16 + l2;
    if (gr < Nrows) {
        if (which) alpha_d[gr * H + h] = v;
        else       alpha_s[gr * H + h] = v;
    }
}

// ---------------- fused per-node max + per-edge packed weights ----------------
// pk[h][e] = (f16(w) << 16) | src   (src < 65536)
__global__ __launch_bounds__(256) void attn_kernel(const float4* __restrict__ as4,
                                                   const float4* __restrict__ ad4,
                                                   const int* __restrict__ row_off,
                                                   const int* __restrict__ csr_src,
                                                   unsigned int* __restrict__ pk, int N, int M) {
    int n = blockIdx.x * 4 + (threadIdx.x >> 6);
    if (n >= N) return;
    int l = threadIdx.x & 63;
    int beg = row_off[n], end = row_off[n + 1];
    float4 mx = make_float4(-1e30f, -1e30f, -1e30f, -1e30f);
    for (int e = beg + l; e < end; e += 64) {
        float4 a = as4[csr_src[e]];
        mx.x = fmaxf(mx.x, a.x); mx.y = fmaxf(mx.y, a.y);
        mx.z = fmaxf(mx.z, a.z); mx.w = fmaxf(mx.w, a.w);
    }
    #pragma unroll
    for (int off = 32; off >= 1; off >>= 1) {
        mx.x = fmaxf(mx.x, __shfl_xor(mx.x, off));
        mx.y = fmaxf(mx.y, __shfl_xor(mx.y, off));
        mx.z = fmaxf(mx.z, __shfl_xor(mx.z, off));
        mx.w = fmaxf(mx.w, __shfl_xor(mx.w, off));
    }
    float4 d = ad4[n];
    float4 m;
    m.x = leaky(mx.x + d.x); m.y = leaky(mx.y + d.y);
    m.z = leaky(mx.z + d.z); m.w = leaky(mx.w + d.w);
    for (int e = beg + l; e < end; e += 64) {
        int s = csr_src[e];
        float4 a = as4[s];
        unsigned int su = (unsigned int)s;
        unsigned int w0 = (unsigned int)__half_as_ushort(__float2half(__expf(leaky(a.x + d.x) - m.x)));
        unsigned int w1 = (unsigned int)__half_as_ushort(__float2half(__expf(leaky(a.y + d.y) - m.y)));
        unsigned int w2 = (unsigned int)__half_as_ushort(__float2half(__expf(leaky(a.z + d.z) - m.z)));
        unsigned int w3 = (unsigned int)__half_as_ushort(__float2half(__expf(leaky(a.w + d.w) - m.w)));
        pk[e]                 = (w0 << 16) | su;
        pk[(size_t)M + e]     = (w1 << 16) | su;
        pk[(size_t)2 * M + e] = (w2 << 16) | su;
        pk[(size_t)3 * M + e] = (w3 << 16) | su;
    }
}

// ---------------- aggregation v10: f16 gathers, packed pk, packed shuffle reduce ----------------
__global__ __launch_bounds__(256) void aggregate_v10(const unsigned short* __restrict__ xh,
                                                     const unsigned int* __restrict__ pk,
                                                     const int* __restrict__ row_off,
                                                     unsigned short* __restrict__ hout,
                                                     int N, int Npad, int M) {
    int i = blockIdx.x;
    int slab = i & 7;
    int h = slab >> 1;
    int t = threadIdx.x;
    int wv = t >> 6;
    int lane = t & 63;
    int slot = lane >> 4;
    int l16 = lane & 15;
    int n = (i >> 3) * 4 + wv;
    if (n >= N) return;
    int beg = row_off[n], end = row_off[n + 1];

    i32x4 rx = make_rsrc(xh + (size_t)slab * Npad * 64, (unsigned int)Npad * 128u);
    i32x4 rp = make_rsrc(pk + (size_t)h * M, (unsigned int)M * 4u);
    int ld8 = l16 << 3;
    int slot4 = slot << 2;

    __half2 acc01 = u2h2(0), acc23 = u2h2(0), den2 = u2h2(0);

    for (int ebase = beg; ebase < end; ebase += 64) {
        int p = amd_buf_load_i32(rp, (ebase + lane) << 2, 0, 0);
        int nrem = end - ebase;
        int jmax = ((nrem < 64 ? nrem : 64) + 7) >> 3;
        for (int j = 0; j < jmax; ++j) {
            int addr = (j << 5) + slot4;
            int sp0 = __builtin_amdgcn_ds_bpermute(addr, p);
            int sp1 = __builtin_amdgcn_ds_bpermute(addr + 16, p);
            int e0 = ebase + (j << 3) + slot;
            i32x2 ga = amd_buf_load_i32x2(rx, ((sp0 & 0xffff) << 7) + ld8, 0, 0);
            i32x2 gb = amd_buf_load_i32x2(rx, ((sp1 & 0xffff) << 7) + ld8, 0, 0);
            unsigned int wa2 = __builtin_amdgcn_perm(sp0, sp0, 0x03020302);
            unsigned int wb2 = __builtin_amdgcn_perm(sp1, sp1, 0x03020302);
            if (e0 >= end) wa2 = 0u;
            if (e0 + 4 >= end) wb2 = 0u;
            __half2 wha = u2h2(wa2), whb = u2h2(wb2);
            acc01 = __hfma2(wha, u2h2((unsigned int)ga.x), acc01);
            acc23 = __hfma2(wha, u2h2((unsigned int)ga.y), acc23);
            acc01 = __hfma2(whb, u2h2((unsigned int)gb.x), acc01);
            acc23 = __hfma2(whb, u2h2((unsigned int)gb.y), acc23);
            den2 = __hadd2(den2, wha);
            den2 = __hadd2(den2, whb);
        }
    }

    // packed cross-slot reduce (lane bits 4,5): 3 values x 2 levels
    #pragma unroll
    for (int off = 16; off <= 32; off <<= 1) {
        acc01 = __hadd2(acc01, u2h2((unsigned int)__shfl_xor((int)h22u(acc01), off)));
        acc23 = __hadd2(acc23, u2h2((unsigned int)__shfl_xor((int)h22u(acc23), off)));
        den2  = __hadd2(den2,  u2h2((unsigned int)__shfl_xor((int)h22u(den2),  off)));
    }

    if (slot == 0) {
        float2 f01 = __half22float2(acc01);
        float2 f23 = __half22float2(acc23);
        float inv = 1.f / __half2float(__low2half(den2));
        uint2 o;
        o.x = f2bf_bits(f01.x * inv) | (f2bf_bits(f01.y * inv) << 16);
        o.y = f2bf_bits(f23.x * inv) | (f2bf_bits(f23.y * inv) << 16);
        ((uint2*)hout)[((size_t)slab * Npad + n) * 16 + l16] = o;
    }
}

// ---------------- head mean + bias -> bf16 feats ----------------
__global__ void combine_kernel(const unsigned short* __restrict__ hout,
                               const float* __restrict__ bias,
                               unsigned short* __restrict__ featsbf, int N, int Npad) {
    int i = blockIdx.x * blockDim.x + threadIdx.x;   // dword index over [N][64]
    if (i >= N * 64) return;
    int n = i >> 6, c2 = i & 63;
    int chalf = c2 >> 5, ld = c2 & 31;
    const unsigned int* hp = (const unsigned int*)hout;
    float lo = 0.f, hi = 0.f;
    #pragma unroll
    for (int h = 0; h < 4; ++h) {
        unsigned int v = hp[((size_t)(h * 2 + chalf) * Npad + n) * 32 + ld];
        lo += bflo(v); hi += bfhi(v);
    }
    lo = 0.25f * lo + bias[c2 * 2];
    hi = 0.25f * hi + bias[c2 * 2 + 1];
    ((unsigned int*)featsbf)[(size_t)n * 64 + c2] = f2bf_bits(lo) | (f2bf_bits(hi) << 16);
}

// ---------------- pairwise scorer: 32 lanes per pair, 8 pairs/block ----------------
__global__ __launch_bounds__(256) void pair_kernel(const unsigned short* __restrict__ featsbf,
                                                   const float* __restrict__ x,
                                                   const int* __restrict__ idx, int P,
                                                   const float* __restrict__ fc_w,
                                                   const float* __restrict__ fc_b,
                                                   float* __restrict__ out) {
    int p = blockIdx.x * 8 + (threadIdx.x >> 5);
    int l = threadIdx.x & 31;
    if (p >= P) return;
    int i0 = idx[p], i1 = idx[P + p];
    uint2 a = ((const uint2*)featsbf)[(size_t)i0 * 32 + l];
    uint2 b = ((const uint2*)featsbf)[(size_t)i1 * 32 + l];
    float s = bflo(a.x) * bflo(b.x) + bfhi(a.x) * bfhi(b.x)
            + bflo(a.y) * bflo(b.y) + bfhi(a.y) * bfhi(b.y);
    #pragma unroll
    for (int off = 16; off >= 1; off >>= 1) s += __shfl_xor(s, off);
    if (l == 0) {
        float2 c0 = *(const float2*)&x[(size_t)i0 * 130];
        float2 c1 = *(const float2*)&x[(size_t)i1 * 130];
        float dx = c0.x - c1.x;
        float dy = c0.y - c1.y;
        float pe = dx * dx + dy * dy;
        out[p] = fc_w[0] * s + fc_w[1] * pe + fc_b[0];
    }
}

extern "C" void kernel_launch(void* const* d_in, const int* in_sizes, int n_in,
                              void* d_out, int out_size, void* d_ws, size_t ws_size,
                              hipStream_t stream) {
    const float* x   = (const float*)d_in[0];
    const int*   ei  = (const int*)d_in[1];
    const int*   idx = (const int*)d_in[2];
    const float* W1  = (const float*)d_in[3];
    const float* as1 = (const float*)d_in[4];
    const float* ad1 = (const float*)d_in[5];
    const float* b1  = (const float*)d_in[6];
    const float* W2  = (const float*)d_in[7];
    const float* as2 = (const float*)d_in[8];
    const float* ad2 = (const float*)d_in[9];
    const float* b2  = (const float*)d_in[10];
    const float* fcw = (const float*)d_in[11];
    const float* fcb = (const float*)d_in[12];
    float* out = (float*)d_out;

    const int N = in_sizes[0] / 130;
    const int E = in_sizes[1] / 2;
    const int P = in_sizes[2] / 2;
    const int M = E + N;
    const int Npad = (N + 127) & ~127;

    char* ws = (char*)d_ws;
    size_t off = 0;
    auto alloc = [&](size_t bytes) -> void* {
        void* p = ws + off;
        off += (bytes + 255) & ~(size_t)255;
        return p;
    };
    unsigned short* xh_f16  = (unsigned short*)alloc((size_t)Npad * FOUT * 2);
    unsigned short* hout    = (unsigned short*)alloc((size_t)Npad * FOUT * 2);
    unsigned short* featsbf = (unsigned short*)alloc((size_t)Npad * C * 2);
    unsigned short* Wt1     = (unsigned short*)alloc((size_t)128 * FOUT * 2);
    unsigned short* Wt2     = (unsigned short*)alloc((size_t)128 * FOUT * 2);
    float*          alpha_s = (float*)alloc((size_t)N * H * 4);
    float*          alpha_d = (float*)alloc((size_t)N * H * 4);
    unsigned int*   pk      = (unsigned int*)alloc((size_t)M * H * 4);
    int*            row_off = (int*)alloc((size_t)(N + 1) * 4);
    int*            cursor  = (int*)alloc((size_t)N * 4);
    int*            counts  = (int*)alloc((size_t)N * 4);
    int*            csr_src = (int*)alloc((size_t)M * 4);

    // prep (weights + zero counts), then CSR by dst (shared across both layers)
    prep_kernel<<<(128 * FOUT + 255) / 256, 256, 0, stream>>>(W1, W2, Wt1, Wt2, counts, N);
    hist_kernel<<<(M + 255) / 256, 256, 0, stream>>>(ei, E, N, counts);
    scan_kernel<<<1, 256, 0, stream>>>(counts, row_off, cursor, N);
    scatter_kernel<<<(M + 255) / 256, 256, 0, stream>>>(ei, E, N, cursor, csr_src);

    dim3 ggrid(H, Npad / 128);
    int aggGrid = ((N + 3) / 4) * 8;
    int cmbGrid = (N * 64 + 255) / 256;

    // layer 1 (A = x directly, fused conversion)
    gemm_v4<true><<<ggrid, 256, 0, stream>>>(x, N, Wt1, as1, ad1, xh_f16, alpha_s, alpha_d, Npad);
    attn_kernel<<<(N + 3) / 4, 256, 0, stream>>>((const float4*)alpha_s, (const float4*)alpha_d,
                                                 row_off, csr_src, pk, N, M);
    aggregate_v10<<<aggGrid, 256, 0, stream>>>(xh_f16, pk, row_off, hout, N, Npad, M);
    combine_kernel<<<cmbGrid, 256, 0, stream>>>(hout, b1, featsbf, N, Npad);

    // layer 2 (A = featsbf, buffer-OOB handles pad rows)
    gemm_v4<false><<<ggrid, 256, 0, stream>>>(featsbf, N, Wt2, as2, ad2, xh_f16, alpha_s, alpha_d, Npad);
    attn_kernel<<<(N + 3) / 4, 256, 0, stream>>>((const float4*)alpha_s, (const float4*)alpha_d,
                                                 row_off, csr_src, pk, N, M);
    aggregate_v10<<<aggGrid, 256, 0, stream>>>(xh_f16, pk, row_off, hout, N, Npad, M);
    combine_kernel<<<cmbGrid, 256, 0, stream>>>(hout, b2, featsbf, N, Npad);

    // pairwise output
    pair_kernel<<<(P + 7) / 8, 256, 0, stream>>>(featsbf, x, idx, P, fcw, fcb, out);
}

// Round 11
// 227.406 us; speedup vs baseline: 1.3069x; 1.1917x over previous
//
#include <hip/hip_runtime.h>
#include <hip/hip_fp16.h>

#define H 4
#define C 128
#define FOUT 512

typedef __attribute__((ext_vector_type(8))) short s16x8;
typedef __attribute__((ext_vector_type(4))) float f32x4;
typedef __attribute__((ext_vector_type(4))) int i32x4;
typedef __attribute__((ext_vector_type(2))) int i32x2;

// CK-style raw buffer-load intrinsics (32-bit voffset addressing)
__device__ int amd_buf_load_i32(i32x4 rsrc, int voffset, int soffset, int aux) __asm("llvm.amdgcn.raw.buffer.load.i32");
__device__ i32x2 amd_buf_load_i32x2(i32x4 rsrc, int voffset, int soffset, int aux) __asm("llvm.amdgcn.raw.buffer.load.v2i32");
__device__ i32x4 amd_buf_load_i32x4(i32x4 rsrc, int voffset, int soffset, int aux) __asm("llvm.amdgcn.raw.buffer.load.v4i32");

__device__ __forceinline__ i32x4 make_rsrc(const void* p, unsigned int bytes) {
    i32x4 r;
    r.x = (int)(unsigned int)(unsigned long long)p;
    r.y = (int)(unsigned int)(((unsigned long long)p) >> 32);
    r.z = (int)bytes;          // num_records; OOB load returns 0
    r.w = 0x00020000;          // raw untyped dword access
    return r;
}

__device__ __forceinline__ unsigned int f2bf_bits(float f) {
    unsigned int u = __float_as_uint(f);
    u += 0x7fffu + ((u >> 16) & 1u);
    return u >> 16;
}
__device__ __forceinline__ unsigned int pack2bf(unsigned int u0, unsigned int u1) {
    unsigned int r0 = (u0 + 0x7fffu + ((u0 >> 16) & 1u)) >> 16;
    unsigned int r1 = (u1 + 0x7fffu + ((u1 >> 16) & 1u)) & 0xffff0000u;
    return r0 | r1;
}
__device__ __forceinline__ float bflo(unsigned int u) { return __uint_as_float(u << 16); }
__device__ __forceinline__ float bfhi(unsigned int u) { return __uint_as_float(u & 0xffff0000u); }
__device__ __forceinline__ float leaky(float x) { return (x >= 0.f) ? x : 0.2f * x; }
__device__ __forceinline__ __half2 u2h2(unsigned int u) {
    union { unsigned int u; __half2 h; } c; c.u = u; return c.h;
}
__device__ __forceinline__ unsigned int h22u(__half2 h) {
    union { __half2 h; unsigned int u; } c; c.h = h; return c.u;
}
__device__ __forceinline__ unsigned int pkrtz_bits(float a, float b) {
    auto v = __builtin_amdgcn_cvt_pkrtz(a, b);
    union { decltype(v) h; unsigned int u; } c; c.h = v; return c.u;
}

// ---------------- prep (convert weights) || hist, fused by blockIdx ----------------
// counts pre-zeroed by hipMemsetAsync before this launch.
__global__ void prep_hist(const float* __restrict__ W1, const float* __restrict__ W2,
                          unsigned short* __restrict__ Wt1, unsigned short* __restrict__ Wt2,
                          int* __restrict__ counts, const int* __restrict__ ei, int E, int N) {
    int b = blockIdx.x;
    if (b < 256) {
        int i = b * 256 + threadIdx.x;
        if (i < 128 * 512) {
            int c = i >> 7, k = i & 127;
            Wt1[i] = (unsigned short)f2bf_bits(W1[(size_t)k * FOUT + c]);
            Wt2[i] = (unsigned short)f2bf_bits(W2[(size_t)k * FOUT + c]);
        }
    } else {
        int e = (b - 256) * 256 + threadIdx.x;
        int M = E + N;
        if (e < M) {
            int d = (e < E) ? ei[E + e] : (e - E);
            atomicAdd(&counts[d], 1);
        }
    }
}

// ---------------- scan: 1024 threads, int4 vectorized ----------------
__global__ __launch_bounds__(1024) void scan_kernel(const int* __restrict__ counts,
                                                    int* __restrict__ row_off,
                                                    int* __restrict__ cursor, int N) {
    __shared__ int part[1024];
    int t = threadIdx.x;
    int chunk = (((N + 1023) >> 10) + 3) & ~3;
    int b = t * chunk; if (b > N) b = N;
    int e = b + chunk; if (e > N) e = N;
    int s = 0;
    int i = b;
    for (; i + 3 < e; i += 4) {
        int4 v = *(const int4*)&counts[i];
        s += v.x + v.y + v.z + v.w;
    }
    for (; i < e; ++i) s += counts[i];
    part[t] = s;
    __syncthreads();
    for (int off = 1; off < 1024; off <<= 1) {
        int v = (t >= off) ? part[t - off] : 0;
        __syncthreads();
        part[t] += v;
        __syncthreads();
    }
    int run = (t == 0) ? 0 : part[t - 1];
    i = b;
    for (; i + 3 < e; i += 4) {
        int4 c = *(const int4*)&counts[i];
        int4 r;
        r.x = run; r.y = run + c.x; r.z = r.y + c.y; r.w = r.z + c.z;
        *(int4*)&row_off[i] = r;
        *(int4*)&cursor[i] = r;
        run = r.w + c.w;
    }
    for (; i < e; ++i) { row_off[i] = run; cursor[i] = run; run += counts[i]; }
    if (t == 1023) row_off[N] = part[1023];
}

// ---------------- MFMA GEMM body (device fn): buffer-load A, swapped operands ----------------
template <bool IS_X>
__device__ __forceinline__ void gemm_body(int h, int r0, const void* __restrict__ Asrc, int Nrows,
                                          const unsigned short* __restrict__ Bt,
                                          const float* __restrict__ a_src,
                                          const float* __restrict__ a_dst,
                                          unsigned short* __restrict__ Xh,
                                          float* __restrict__ alpha_s,
                                          float* __restrict__ alpha_d,
                                          int Npad, float (*albuf)[4][16][2][2]) {
    int t = threadIdx.x;
    int lane = t & 63;
    int wv = t >> 6;
    int wr = wv >> 1, wc = wv & 1;
    int lr = lane & 15;
    int ksel = lane >> 4;

    i32x4 rA = make_rsrc(Asrc, IS_X ? (unsigned int)Nrows * 520u : (unsigned int)Nrows * 256u);

    f32x4 acc[4][4];
    #pragma unroll
    for (int i = 0; i < 4; ++i)
        #pragma unroll
        for (int j = 0; j < 4; ++j) acc[i][j] = (f32x4){0.f, 0.f, 0.f, 0.f};

    const s16x8* Bb = (const s16x8*)(Bt + (size_t)(h * 128 + wc * 64 + lr) * C);

    #pragma unroll
    for (int ks = 0; ks < 4; ++ks) {
        int cb = ks * 4 + ksel;
        s16x8 af[4], bf[4];
        #pragma unroll
        for (int i = 0; i < 4; ++i) {
            int gr = r0 + wr * 64 + i * 16 + lr;
            if constexpr (IS_X) {
                int base = gr * 520 + 8 + cb * 32;
                i32x2 u0 = amd_buf_load_i32x2(rA, base, 0, 0);
                i32x2 u1 = amd_buf_load_i32x2(rA, base + 8, 0, 0);
                i32x2 u2 = amd_buf_load_i32x2(rA, base + 16, 0, 0);
                i32x2 u3 = amd_buf_load_i32x2(rA, base + 24, 0, 0);
                i32x4 packed;
                packed.x = (int)pack2bf((unsigned int)u0.x, (unsigned int)u0.y);
                packed.y = (int)pack2bf((unsigned int)u1.x, (unsigned int)u1.y);
                packed.z = (int)pack2bf((unsigned int)u2.x, (unsigned int)u2.y);
                packed.w = (int)pack2bf((unsigned int)u3.x, (unsigned int)u3.y);
                af[i] = __builtin_bit_cast(s16x8, packed);
            } else {
                i32x4 v = amd_buf_load_i32x4(rA, gr * 256 + cb * 16, 0, 0);
                af[i] = __builtin_bit_cast(s16x8, v);
            }
            bf[i] = Bb[(size_t)(i * 16) * 16 + cb];
        }
        #pragma unroll
        for (int i = 0; i < 4; ++i)
            #pragma unroll
            for (int j = 0; j < 4; ++j)
                acc[i][j] = __builtin_amdgcn_mfma_f32_16x16x32_bf16(bf[j], af[i], acc[i][j], 0, 0, 0);
    }

    float4 avj[4], dvj[4];
    #pragma unroll
    for (int j = 0; j < 4; ++j) {
        int cc = h * C + wc * 64 + j * 16 + ksel * 4;
        avj[j] = *(const float4*)&a_src[cc];
        dvj[j] = *(const float4*)&a_dst[cc];
    }

    unsigned short* slabp = Xh + (size_t)(h * 2 + wc) * Npad * 64;
    float ps[4] = {0.f, 0.f, 0.f, 0.f}, pd[4] = {0.f, 0.f, 0.f, 0.f};
    #pragma unroll
    for (int i = 0; i < 4; ++i) {
        int gr = r0 + wr * 64 + i * 16 + lr;
        #pragma unroll
        for (int j = 0; j < 4; ++j) {
            f32x4 a4 = acc[i][j];
            ps[i] += a4[0] * avj[j].x + a4[1] * avj[j].y + a4[2] * avj[j].z + a4[3] * avj[j].w;
            pd[i] += a4[0] * dvj[j].x + a4[1] * dvj[j].y + a4[2] * dvj[j].z + a4[3] * dvj[j].w;
            uint2 o;
            o.x = pkrtz_bits(a4[0], a4[1]);
            o.y = pkrtz_bits(a4[2], a4[3]);
            *(uint2*)(slabp + (size_t)gr * 64 + j * 16 + ksel * 4) = o;
        }
        ps[i] += __shfl_xor(ps[i], 16); ps[i] += __shfl_xor(ps[i], 32);
        pd[i] += __shfl_xor(pd[i], 16); pd[i] += __shfl_xor(pd[i], 32);
    }
    if (lane < 16) {
        #pragma unroll
        for (int i = 0; i < 4; ++i) {
            albuf[wr][i][lane][wc][0] = ps[i];
            albuf[wr][i][lane][wc][1] = pd[i];
        }
    }
    __syncthreads();

    int rid = t >> 1, which = t & 1;
    int wr2 = rid >> 6, rem = rid & 63, i2 = rem >> 4, l2 = rem & 15;
    float v = albuf[wr2][i2][l2][0][which] + albuf[wr2][i2][l2][1][which];
    int gr = r0 + wr2 * 64 + i2 * 16 + l2;
    if (gr < Nrows) {
        if (which) alpha_d[gr * H + h] = v;
        else       alpha_s[gr * H + h] = v;
    }
}

// ---------------- scatter || gemm1, fused by blockIdx ----------------
__global__ __launch_bounds__(256) void scatter_gemm1(const int* __restrict__ ei, int E, int N,
                                                     int* __restrict__ cursor, int* __restrict__ csr_src,
                                                     const float* __restrict__ x,
                                                     const unsigned short* __restrict__ Wt1,
                                                     const float* __restrict__ as1,
                                                     const float* __restrict__ ad1,
                                                     unsigned short* __restrict__ Xh,
                                                     float* __restrict__ alpha_s,
                                                     float* __restrict__ alpha_d,
                                                     int Npad, int nScatterBlocks) {
    __shared__ float albuf[2][4][16][2][2];
    int b = blockIdx.x;
    if (b < nScatterBlocks) {
        int e = b * 256 + threadIdx.x;
        int M = E + N;
        if (e < M) {
            int s = (e < E) ? ei[e] : (e - E);
            int d = (e < E) ? ei[E + e] : (e - E);
            int pos = atomicAdd(&cursor[d], 1);
            csr_src[pos] = s;
        }
    } else {
        int gb = b - nScatterBlocks;
        gemm_body<true>(gb & 3, (gb >> 2) * 128, x, N, Wt1, as1, ad1, Xh, alpha_s, alpha_d, Npad, albuf);
    }
}

// ---------------- standalone gemm (layer 2) ----------------
__global__ __launch_bounds__(256) void gemm2_kernel(const unsigned short* __restrict__ featsbf, int N,
                                                    const unsigned short* __restrict__ Wt2,
                                                    const float* __restrict__ as2,
                                                    const float* __restrict__ ad2,
                                                    unsigned short* __restrict__ Xh,
                                                    float* __restrict__ alpha_s,
                                                    float* __restrict__ alpha_d, int Npad) {
    __shared__ float albuf[2][4][16][2][2];
    int gb = blockIdx.x;
    gemm_body<false>(gb & 3, (gb >> 2) * 128, featsbf, N, Wt2, as2, ad2, Xh, alpha_s, alpha_d, Npad, albuf);
}

// ---------------- fused per-node max + per-edge packed weights ----------------
// pk[h][e] = (f16(w) << 16) | src   (src < 65536)
__global__ __launch_bounds__(256) void attn_kernel(const float4* __restrict__ as4,
                                                   const float4* __restrict__ ad4,
                                                   const int* __restrict__ row_off,
                                                   const int* __restrict__ csr_src,
                                                   unsigned int* __restrict__ pk, int N, int M) {
    int n = blockIdx.x * 4 + (threadIdx.x >> 6);
    if (n >= N) return;
    int l = threadIdx.x & 63;
    int beg = row_off[n], end = row_off[n + 1];
    float4 mx = make_float4(-1e30f, -1e30f, -1e30f, -1e30f);
    for (int e = beg + l; e < end; e += 64) {
        float4 a = as4[csr_src[e]];
        mx.x = fmaxf(mx.x, a.x); mx.y = fmaxf(mx.y, a.y);
        mx.z = fmaxf(mx.z, a.z); mx.w = fmaxf(mx.w, a.w);
    }
    #pragma unroll
    for (int off = 32; off >= 1; off >>= 1) {
        mx.x = fmaxf(mx.x, __shfl_xor(mx.x, off));
        mx.y = fmaxf(mx.y, __shfl_xor(mx.y, off));
        mx.z = fmaxf(mx.z, __shfl_xor(mx.z, off));
        mx.w = fmaxf(mx.w, __shfl_xor(mx.w, off));
    }
    float4 d = ad4[n];
    float4 m;
    m.x = leaky(mx.x + d.x); m.y = leaky(mx.y + d.y);
    m.z = leaky(mx.z + d.z); m.w = leaky(mx.w + d.w);
    for (int e = beg + l; e < end; e += 64) {
        int s = csr_src[e];
        float4 a = as4[s];
        unsigned int su = (unsigned int)s;
        unsigned int w0 = (unsigned int)__half_as_ushort(__float2half(__expf(leaky(a.x + d.x) - m.x)));
        unsigned int w1 = (unsigned int)__half_as_ushort(__float2half(__expf(leaky(a.y + d.y) - m.y)));
        unsigned int w2 = (unsigned int)__half_as_ushort(__float2half(__expf(leaky(a.z + d.z) - m.z)));
        unsigned int w3 = (unsigned int)__half_as_ushort(__float2half(__expf(leaky(a.w + d.w) - m.w)));
        pk[e]                 = (w0 << 16) | su;
        pk[(size_t)M + e]     = (w1 << 16) | su;
        pk[(size_t)2 * M + e] = (w2 << 16) | su;
        pk[(size_t)3 * M + e] = (w3 << 16) | su;
    }
}

// ---------------- aggregation v11: 2 nodes per wave, f16 gathers, packed pk ----------------
__global__ __launch_bounds__(256) void aggregate_v11(const unsigned short* __restrict__ xh,
                                                     const unsigned int* __restrict__ pk,
                                                     const int* __restrict__ row_off,
                                                     unsigned short* __restrict__ hout,
                                                     int N, int Npad, int M) {
    int i = blockIdx.x;
    int slab = i & 7;
    int h = slab >> 1;
    int t = threadIdx.x;
    int wv = t >> 6;
    int lane = t & 63;
    int slot = lane >> 4;
    int l16 = lane & 15;
    int nbase = ((i >> 3) * 4 + wv) * 2;
    if (nbase >= N) return;

    i32x4 rx = make_rsrc(xh + (size_t)slab * Npad * 64, (unsigned int)Npad * 128u);
    i32x4 rp = make_rsrc(pk + (size_t)h * M, (unsigned int)M * 4u);
    int ld8 = l16 << 3;
    int slot4 = slot << 2;
    int nend = (nbase + 2 < N) ? nbase + 2 : N;

    for (int n = nbase; n < nend; ++n) {
        int beg = row_off[n], end = row_off[n + 1];
        __half2 acc01 = u2h2(0), acc23 = u2h2(0), den2 = u2h2(0);

        for (int ebase = beg; ebase < end; ebase += 64) {
            int p = amd_buf_load_i32(rp, (ebase + lane) << 2, 0, 0);
            int nrem = end - ebase;
            int jmax = ((nrem < 64 ? nrem : 64) + 7) >> 3;
            for (int j = 0; j < jmax; ++j) {
                int addr = (j << 5) + slot4;
                int sp0 = __builtin_amdgcn_ds_bpermute(addr, p);
                int sp1 = __builtin_amdgcn_ds_bpermute(addr + 16, p);
                int e0 = ebase + (j << 3) + slot;
                i32x2 ga = amd_buf_load_i32x2(rx, ((sp0 & 0xffff) << 7) + ld8, 0, 0);
                i32x2 gb = amd_buf_load_i32x2(rx, ((sp1 & 0xffff) << 7) + ld8, 0, 0);
                unsigned int wa2 = __builtin_amdgcn_perm(sp0, sp0, 0x03020302);
                unsigned int wb2 = __builtin_amdgcn_perm(sp1, sp1, 0x03020302);
                if (e0 >= end) wa2 = 0u;
                if (e0 + 4 >= end) wb2 = 0u;
                __half2 wha = u2h2(wa2), whb = u2h2(wb2);
                acc01 = __hfma2(wha, u2h2((unsigned int)ga.x), acc01);
                acc23 = __hfma2(wha, u2h2((unsigned int)ga.y), acc23);
                acc01 = __hfma2(whb, u2h2((unsigned int)gb.x), acc01);
                acc23 = __hfma2(whb, u2h2((unsigned int)gb.y), acc23);
                den2 = __hadd2(den2, wha);
                den2 = __hadd2(den2, whb);
            }
        }

        #pragma unroll
        for (int off = 16; off <= 32; off <<= 1) {
            acc01 = __hadd2(acc01, u2h2((unsigned int)__shfl_xor((int)h22u(acc01), off)));
            acc23 = __hadd2(acc23, u2h2((unsigned int)__shfl_xor((int)h22u(acc23), off)));
            den2  = __hadd2(den2,  u2h2((unsigned int)__shfl_xor((int)h22u(den2),  off)));
        }

        if (slot == 0) {
            float2 f01 = __half22float2(acc01);
            float2 f23 = __half22float2(acc23);
            float inv = 1.f / __half2float(__low2half(den2));
            uint2 o;
            o.x = f2bf_bits(f01.x * inv) | (f2bf_bits(f01.y * inv) << 16);
            o.y = f2bf_bits(f23.x * inv) | (f2bf_bits(f23.y * inv) << 16);
            ((uint2*)hout)[((size_t)slab * Npad + n) * 16 + l16] = o;
        }
    }
}

// ---------------- head mean + bias -> bf16 feats (+ optional out init for pair) ----------------
__global__ void combine_kernel(const unsigned short* __restrict__ hout,
                               const float* __restrict__ bias,
                               unsigned short* __restrict__ featsbf, int N, int Npad,
                               float* __restrict__ out, const float* __restrict__ fcb, int P) {
    int i = blockIdx.x * blockDim.x + threadIdx.x;   // dword index over [N][64]
    if (out != nullptr && i < P) out[i] = fcb[0];
    if (i >= N * 64) return;
    int n = i >> 6, c2 = i & 63;
    int chalf = c2 >> 5, ld = c2 & 31;
    const unsigned int* hp = (const unsigned int*)hout;
    float lo = 0.f, hi = 0.f;
    #pragma unroll
    for (int h = 0; h < 4; ++h) {
        unsigned int v = hp[((size_t)(h * 2 + chalf) * Npad + n) * 32 + ld];
        lo += bflo(v); hi += bfhi(v);
    }
    lo = 0.25f * lo + bias[c2 * 2];
    hi = 0.25f * hi + bias[c2 * 2 + 1];
    ((unsigned int*)featsbf)[(size_t)n * 64 + c2] = f2bf_bits(lo) | (f2bf_bits(hi) << 16);
}

// ---------------- pairwise scorer: chalf-split, XCD parity pinned, atomic combine ----------------
// blockIdx&1 = channel half -> L2 working set 2.56MB per XCD (parity-pinned under round-robin).
__global__ __launch_bounds__(256) void pair_kernel(const unsigned short* __restrict__ featsbf,
                                                   const float* __restrict__ x,
                                                   const int* __restrict__ idx, int P,
                                                   const float* __restrict__ fc_w,
                                                   float* __restrict__ out) {
    int chalf = blockIdx.x & 1;
    int p = (blockIdx.x >> 1) * 16 + (threadIdx.x >> 4);
    int l = threadIdx.x & 15;
    if (p >= P) return;
    int i0 = idx[p], i1 = idx[P + p];
    uint2 a = ((const uint2*)featsbf)[(size_t)i0 * 32 + chalf * 16 + l];
    uint2 b = ((const uint2*)featsbf)[(size_t)i1 * 32 + chalf * 16 + l];
    float s = bflo(a.x) * bflo(b.x) + bfhi(a.x) * bfhi(b.x)
            + bflo(a.y) * bflo(b.y) + bfhi(a.y) * bfhi(b.y);
    s += __shfl_xor(s, 1); s += __shfl_xor(s, 2);
    s += __shfl_xor(s, 4); s += __shfl_xor(s, 8);
    if (l == 0) {
        float v = fc_w[0] * s;
        if (chalf == 0) {
            float2 c0 = *(const float2*)&x[(size_t)i0 * 130];
            float2 c1 = *(const float2*)&x[(size_t)i1 * 130];
            float dx = c0.x - c1.x;
            float dy = c0.y - c1.y;
            v += fc_w[1] * (dx * dx + dy * dy);
        }
        atomicAdd(&out[p], v);
    }
}

extern "C" void kernel_launch(void* const* d_in, const int* in_sizes, int n_in,
                              void* d_out, int out_size, void* d_ws, size_t ws_size,
                              hipStream_t stream) {
    const float* x   = (const float*)d_in[0];
    const int*   ei  = (const int*)d_in[1];
    const int*   idx = (const int*)d_in[2];
    const float* W1  = (const float*)d_in[3];
    const float* as1 = (const float*)d_in[4];
    const float* ad1 = (const float*)d_in[5];
    const float* b1  = (const float*)d_in[6];
    const float* W2  = (const float*)d_in[7];
    const float* as2 = (const float*)d_in[8];
    const float* ad2 = (const float*)d_in[9];
    const float* b2  = (const float*)d_in[10];
    const float* fcw = (const float*)d_in[11];
    const float* fcb = (const float*)d_in[12];
    float* out = (float*)d_out;

    const int N = in_sizes[0] / 130;
    const int E = in_sizes[1] / 2;
    const int P = in_sizes[2] / 2;
    const int M = E + N;
    const int Npad = (N + 127) & ~127;

    char* ws = (char*)d_ws;
    size_t off = 0;
    auto alloc = [&](size_t bytes) -> void* {
        void* p = ws + off;
        off += (bytes + 255) & ~(size_t)255;
        return p;
    };
    unsigned short* xh_f16  = (unsigned short*)alloc((size_t)Npad * FOUT * 2);
    unsigned short* hout    = (unsigned short*)alloc((size_t)Npad * FOUT * 2);
    unsigned short* featsbf = (unsigned short*)alloc((size_t)Npad * C * 2);
    unsigned short* Wt1     = (unsigned short*)alloc((size_t)128 * FOUT * 2);
    unsigned short* Wt2     = (unsigned short*)alloc((size_t)128 * FOUT * 2);
    float*          alpha_s = (float*)alloc((size_t)N * H * 4);
    float*          alpha_d = (float*)alloc((size_t)N * H * 4);
    unsigned int*   pk      = (unsigned int*)alloc((size_t)M * H * 4);
    int*            row_off = (int*)alloc((size_t)(N + 1) * 4);
    int*            cursor  = (int*)alloc((size_t)N * 4);
    int*            counts  = (int*)alloc((size_t)N * 4);
    int*            csr_src = (int*)alloc((size_t)M * 4);

    const int histBlocks = (M + 255) / 256;
    const int scatBlocks = (M + 255) / 256;
    const int gemmBlocks = 4 * (Npad / 128);
    int aggGrid = ((N + 7) / 8) * 8;
    int cmbGrid = (N * 64 + 255) / 256;

    // counts=0, then (weights-convert || hist), scan, (scatter || gemm1)
    hipMemsetAsync(counts, 0, (size_t)N * 4, stream);
    prep_hist<<<256 + histBlocks, 256, 0, stream>>>(W1, W2, Wt1, Wt2, counts, ei, E, N);
    scan_kernel<<<1, 1024, 0, stream>>>(counts, row_off, cursor, N);
    scatter_gemm1<<<scatBlocks + gemmBlocks, 256, 0, stream>>>(ei, E, N, cursor, csr_src,
                                                               x, Wt1, as1, ad1, xh_f16,
                                                               alpha_s, alpha_d, Npad, scatBlocks);

    // layer 1 rest
    attn_kernel<<<(N + 3) / 4, 256, 0, stream>>>((const float4*)alpha_s, (const float4*)alpha_d,
                                                 row_off, csr_src, pk, N, M);
    aggregate_v11<<<aggGrid, 256, 0, stream>>>(xh_f16, pk, row_off, hout, N, Npad, M);
    combine_kernel<<<cmbGrid, 256, 0, stream>>>(hout, b1, featsbf, N, Npad, nullptr, fcb, 0);

    // layer 2
    gemm2_kernel<<<gemmBlocks, 256, 0, stream>>>(featsbf, N, Wt2, as2, ad2, xh_f16,
                                                 alpha_s, alpha_d, Npad);
    attn_kernel<<<(N + 3) / 4, 256, 0, stream>>>((const float4*)alpha_s, (const float4*)alpha_d,
                                                 row_off, csr_src, pk, N, M);
    aggregate_v11<<<aggGrid, 256, 0, stream>>>(xh_f16, pk, row_off, hout, N, Npad, M);
    combine_kernel<<<cmbGrid, 256, 0, stream>>>(hout, b2, featsbf, N, Npad, out, fcb, P);

    // pairwise output (chalf-split, accumulates into out initialized by combine above)
    pair_kernel<<<((P + 15) / 16) * 2, 256, 0, stream>>>(featsbf, x, idx, P, fcw, out);
}

// Round 12
// 224.565 us; speedup vs baseline: 1.3234x; 1.0127x over previous
//
#include <hip/hip_runtime.h>
#include <hip/hip_fp16.h>

#define H 4
#define C 128
#define FOUT 512

typedef __attribute__((ext_vector_type(8))) short s16x8;
typedef __attribute__((ext_vector_type(4))) float f32x4;
typedef __attribute__((ext_vector_type(4))) int i32x4;
typedef __attribute__((ext_vector_type(2))) int i32x2;

// CK-style raw buffer-load intrinsics (32-bit voffset addressing)
__device__ int amd_buf_load_i32(i32x4 rsrc, int voffset, int soffset, int aux) __asm("llvm.amdgcn.raw.buffer.load.i32");
__device__ i32x2 amd_buf_load_i32x2(i32x4 rsrc, int voffset, int soffset, int aux) __asm("llvm.amdgcn.raw.buffer.load.v2i32");
__device__ i32x4 amd_buf_load_i32x4(i32x4 rsrc, int voffset, int soffset, int aux) __asm("llvm.amdgcn.raw.buffer.load.v4i32");

__device__ __forceinline__ i32x4 make_rsrc(const void* p, unsigned int bytes) {
    i32x4 r;
    r.x = (int)(unsigned int)(unsigned long long)p;
    r.y = (int)(unsigned int)(((unsigned long long)p) >> 32);
    r.z = (int)bytes;          // num_records; OOB load returns 0
    r.w = 0x00020000;          // raw untyped dword access
    return r;
}

__device__ __forceinline__ unsigned int f2bf_bits(float f) {
    unsigned int u = __float_as_uint(f);
    u += 0x7fffu + ((u >> 16) & 1u);
    return u >> 16;
}
__device__ __forceinline__ unsigned int pack2bf(unsigned int u0, unsigned int u1) {
    unsigned int r0 = (u0 + 0x7fffu + ((u0 >> 16) & 1u)) >> 16;
    unsigned int r1 = (u1 + 0x7fffu + ((u1 >> 16) & 1u)) & 0xffff0000u;
    return r0 | r1;
}
__device__ __forceinline__ float bflo(unsigned int u) { return __uint_as_float(u << 16); }
__device__ __forceinline__ float bfhi(unsigned int u) { return __uint_as_float(u & 0xffff0000u); }
__device__ __forceinline__ float leaky(float x) { return (x >= 0.f) ? x : 0.2f * x; }
__device__ __forceinline__ __half2 u2h2(unsigned int u) {
    union { unsigned int u; __half2 h; } c; c.u = u; return c.h;
}
__device__ __forceinline__ unsigned int h22u(__half2 h) {
    union { __half2 h; unsigned int u; } c; c.h = h; return c.u;
}
__device__ __forceinline__ unsigned int pkrtz_bits(float a, float b) {
    auto v = __builtin_amdgcn_cvt_pkrtz(a, b);
    union { decltype(v) h; unsigned int u; } c; c.h = v; return c.u;
}

// ---------------- prep (convert weights) || hist, fused by blockIdx ----------------
__global__ void prep_hist(const float* __restrict__ W1, const float* __restrict__ W2,
                          unsigned short* __restrict__ Wt1, unsigned short* __restrict__ Wt2,
                          int* __restrict__ counts, const int* __restrict__ ei, int E, int N) {
    int b = blockIdx.x;
    if (b < 256) {
        int i = b * 256 + threadIdx.x;
        if (i < 128 * 512) {
            int c = i >> 7, k = i & 127;
            Wt1[i] = (unsigned short)f2bf_bits(W1[(size_t)k * FOUT + c]);
            Wt2[i] = (unsigned short)f2bf_bits(W2[(size_t)k * FOUT + c]);
        }
    } else {
        int e = (b - 256) * 256 + threadIdx.x;
        int M = E + N;
        if (e < M) {
            int d = (e < E) ? ei[E + e] : (e - E);
            atomicAdd(&counts[d], 1);
        }
    }
}

// ---------------- scan: 1024 threads, int4 vectorized ----------------
__global__ __launch_bounds__(1024) void scan_kernel(const int* __restrict__ counts,
                                                    int* __restrict__ row_off,
                                                    int* __restrict__ cursor, int N) {
    __shared__ int part[1024];
    int t = threadIdx.x;
    int chunk = (((N + 1023) >> 10) + 3) & ~3;
    int b = t * chunk; if (b > N) b = N;
    int e = b + chunk; if (e > N) e = N;
    int s = 0;
    int i = b;
    for (; i + 3 < e; i += 4) {
        int4 v = *(const int4*)&counts[i];
        s += v.x + v.y + v.z + v.w;
    }
    for (; i < e; ++i) s += counts[i];
    part[t] = s;
    __syncthreads();
    for (int off = 1; off < 1024; off <<= 1) {
        int v = (t >= off) ? part[t - off] : 0;
        __syncthreads();
        part[t] += v;
        __syncthreads();
    }
    int run = (t == 0) ? 0 : part[t - 1];
    i = b;
    for (; i + 3 < e; i += 4) {
        int4 c = *(const int4*)&counts[i];
        int4 r;
        r.x = run; r.y = run + c.x; r.z = r.y + c.y; r.w = r.z + c.z;
        *(int4*)&row_off[i] = r;
        *(int4*)&cursor[i] = r;
        run = r.w + c.w;
    }
    for (; i < e; ++i) { row_off[i] = run; cursor[i] = run; run += counts[i]; }
    if (t == 1023) row_off[N] = part[1023];
}

// ---------------- MFMA GEMM body: coalesced LDS-staged A, swapped operands ----------------
// A-tile (128 rows x 128 ch bf16, 32KB) staged with XOR swizzle cb^(row&7); fragments via ds_read_b128.
template <bool IS_X>
__device__ __forceinline__ void gemm_body(int h, int r0, const void* __restrict__ Asrc, int Nrows,
                                          const unsigned short* __restrict__ Bt,
                                          const float* __restrict__ a_src,
                                          const float* __restrict__ a_dst,
                                          unsigned short* __restrict__ Xh,
                                          float* __restrict__ alpha_s,
                                          float* __restrict__ alpha_d,
                                          int Npad, i32x4* __restrict__ AsTile,
                                          float (*albuf)[4][16][2][2]) {
    int t = threadIdx.x;
    int lane = t & 63;
    int wv = t >> 6;
    int wr = wv >> 1, wc = wv & 1;
    int lr = lane & 15;
    int ksel = lane >> 4;

    // ---- stage A tile (coalesced) ----
    i32x4 rA = make_rsrc(Asrc, IS_X ? (unsigned int)Nrows * 520u : (unsigned int)Nrows * 256u);
    #pragma unroll
    for (int i = 0; i < 8; ++i) {
        int q = t + i * 256;          // 2048 x 16B chunks
        int row = q >> 4, cb = q & 15;
        i32x4 v;
        if constexpr (IS_X) {
            int base = (r0 + row) * 520 + 8 + cb * 32;
            i32x2 u0 = amd_buf_load_i32x2(rA, base, 0, 0);
            i32x2 u1 = amd_buf_load_i32x2(rA, base + 8, 0, 0);
            i32x2 u2 = amd_buf_load_i32x2(rA, base + 16, 0, 0);
            i32x2 u3 = amd_buf_load_i32x2(rA, base + 24, 0, 0);
            v.x = (int)pack2bf((unsigned int)u0.x, (unsigned int)u0.y);
            v.y = (int)pack2bf((unsigned int)u1.x, (unsigned int)u1.y);
            v.z = (int)pack2bf((unsigned int)u2.x, (unsigned int)u2.y);
            v.w = (int)pack2bf((unsigned int)u3.x, (unsigned int)u3.y);
        } else {
            v = amd_buf_load_i32x4(rA, (r0 + row) * 256 + cb * 16, 0, 0);
        }
        AsTile[row * 16 + (cb ^ (row & 7))] = v;
    }
    __syncthreads();

    f32x4 acc[4][4];
    #pragma unroll
    for (int i = 0; i < 4; ++i)
        #pragma unroll
        for (int j = 0; j < 4; ++j) acc[i][j] = (f32x4){0.f, 0.f, 0.f, 0.f};

    const s16x8* Bb = (const s16x8*)(Bt + (size_t)(h * 128 + wc * 64 + lr) * C);

    #pragma unroll
    for (int ks = 0; ks < 4; ++ks) {
        int cb = ks * 4 + ksel;
        s16x8 af[4], bf[4];
        #pragma unroll
        for (int i = 0; i < 4; ++i) {
            int rowl = wr * 64 + i * 16 + lr;
            af[i] = __builtin_bit_cast(s16x8, AsTile[rowl * 16 + (cb ^ (rowl & 7))]);
            bf[i] = Bb[(size_t)(i * 16) * 16 + cb];
        }
        #pragma unroll
        for (int i = 0; i < 4; ++i)
            #pragma unroll
            for (int j = 0; j < 4; ++j)
                acc[i][j] = __builtin_amdgcn_mfma_f32_16x16x32_bf16(bf[j], af[i], acc[i][j], 0, 0, 0);
    }

    float4 avj[4], dvj[4];
    #pragma unroll
    for (int j = 0; j < 4; ++j) {
        int cc = h * C + wc * 64 + j * 16 + ksel * 4;
        avj[j] = *(const float4*)&a_src[cc];
        dvj[j] = *(const float4*)&a_dst[cc];
    }

    unsigned short* slabp = Xh + (size_t)(h * 2 + wc) * Npad * 64;
    float ps[4] = {0.f, 0.f, 0.f, 0.f}, pd[4] = {0.f, 0.f, 0.f, 0.f};
    #pragma unroll
    for (int i = 0; i < 4; ++i) {
        int gr = r0 + wr * 64 + i * 16 + lr;
        #pragma unroll
        for (int j = 0; j < 4; ++j) {
            f32x4 a4 = acc[i][j];
            ps[i] += a4[0] * avj[j].x + a4[1] * avj[j].y + a4[2] * avj[j].z + a4[3] * avj[j].w;
            pd[i] += a4[0] * dvj[j].x + a4[1] * dvj[j].y + a4[2] * dvj[j].z + a4[3] * dvj[j].w;
            uint2 o;
            o.x = pkrtz_bits(a4[0], a4[1]);
            o.y = pkrtz_bits(a4[2], a4[3]);
            *(uint2*)(slabp + (size_t)gr * 64 + j * 16 + ksel * 4) = o;
        }
        ps[i] += __shfl_xor(ps[i], 16); ps[i] += __shfl_xor(ps[i], 32);
        pd[i] += __shfl_xor(pd[i], 16); pd[i] += __shfl_xor(pd[i], 32);
    }
    if (lane < 16) {
        #pragma unroll
        for (int i = 0; i < 4; ++i) {
            albuf[wr][i][lane][wc][0] = ps[i];
            albuf[wr][i][lane][wc][1] = pd[i];
        }
    }
    __syncthreads();

    int rid = t >> 1, which = t & 1;
    int wr2 = rid >> 6, rem = rid & 63, i2 = rem >> 4, l2 = rem & 15;
    float v = albuf[wr2][i2][l2][0][which] + albuf[wr2][i2][l2][1][which];
    int gr = r0 + wr2 * 64 + i2 * 16 + l2;
    if (gr < Nrows) {
        if (which) alpha_d[gr * H + h] = v;
        else       alpha_s[gr * H + h] = v;
    }
}

// ---------------- scatter || gemm1, fused by blockIdx ----------------
__global__ __launch_bounds__(256) void scatter_gemm1(const int* __restrict__ ei, int E, int N,
                                                     int* __restrict__ cursor, int* __restrict__ csr_src,
                                                     const float* __restrict__ x,
                                                     const unsigned short* __restrict__ Wt1,
                                                     const float* __restrict__ as1,
                                                     const float* __restrict__ ad1,
                                                     unsigned short* __restrict__ Xh,
                                                     float* __restrict__ alpha_s,
                                                     float* __restrict__ alpha_d,
                                                     int Npad, int nScatterBlocks) {
    __shared__ i32x4 AsTile[2048];
    __shared__ float albuf[2][4][16][2][2];
    int b = blockIdx.x;
    if (b < nScatterBlocks) {
        int e = b * 256 + threadIdx.x;
        int M = E + N;
        if (e < M) {
            int s = (e < E) ? ei[e] : (e - E);
            int d = (e < E) ? ei[E + e] : (e - E);
            int pos = atomicAdd(&cursor[d], 1);
            csr_src[pos] = s;
        }
    } else {
        int gb = b - nScatterBlocks;
        gemm_body<true>(gb & 3, (gb >> 2) * 128, x, N, Wt1, as1, ad1, Xh, alpha_s, alpha_d,
                        Npad, AsTile, albuf);
    }
}

// ---------------- standalone gemm (layer 2) ----------------
__global__ __launch_bounds__(256) void gemm2_kernel(const unsigned short* __restrict__ featsbf, int N,
                                                    const unsigned short* __restrict__ Wt2,
                                                    const float* __restrict__ as2,
                                                    const float* __restrict__ ad2,
                                                    unsigned short* __restrict__ Xh,
                                                    float* __restrict__ alpha_s,
                                                    float* __restrict__ alpha_d, int Npad) {
    __shared__ i32x4 AsTile[2048];
    __shared__ float albuf[2][4][16][2][2];
    int gb = blockIdx.x;
    gemm_body<false>(gb & 3, (gb >> 2) * 128, featsbf, N, Wt2, as2, ad2, Xh, alpha_s, alpha_d,
                     Npad, AsTile, albuf);
}

// ---------------- fused per-node max + per-edge packed weights ----------------
// pk[h][e] = (f16(w) << 16) | src   (src < 65536)
__global__ __launch_bounds__(256) void attn_kernel(const float4* __restrict__ as4,
                                                   const float4* __restrict__ ad4,
                                                   const int* __restrict__ row_off,
                                                   const int* __restrict__ csr_src,
                                                   unsigned int* __restrict__ pk, int N, int M) {
    int n = blockIdx.x * 4 + (threadIdx.x >> 6);
    if (n >= N) return;
    int l = threadIdx.x & 63;
    int beg = row_off[n], end = row_off[n + 1];
    float4 mx = make_float4(-1e30f, -1e30f, -1e30f, -1e30f);
    for (int e = beg + l; e < end; e += 64) {
        float4 a = as4[csr_src[e]];
        mx.x = fmaxf(mx.x, a.x); mx.y = fmaxf(mx.y, a.y);
        mx.z = fmaxf(mx.z, a.z); mx.w = fmaxf(mx.w, a.w);
    }
    #pragma unroll
    for (int off = 32; off >= 1; off >>= 1) {
        mx.x = fmaxf(mx.x, __shfl_xor(mx.x, off));
        mx.y = fmaxf(mx.y, __shfl_xor(mx.y, off));
        mx.z = fmaxf(mx.z, __shfl_xor(mx.z, off));
        mx.w = fmaxf(mx.w, __shfl_xor(mx.w, off));
    }
    float4 d = ad4[n];
    float4 m;
    m.x = leaky(mx.x + d.x); m.y = leaky(mx.y + d.y);
    m.z = leaky(mx.z + d.z); m.w = leaky(mx.w + d.w);
    for (int e = beg + l; e < end; e += 64) {
        int s = csr_src[e];
        float4 a = as4[s];
        unsigned int su = (unsigned int)s;
        unsigned int w0 = (unsigned int)__half_as_ushort(__float2half(__expf(leaky(a.x + d.x) - m.x)));
        unsigned int w1 = (unsigned int)__half_as_ushort(__float2half(__expf(leaky(a.y + d.y) - m.y)));
        unsigned int w2 = (unsigned int)__half_as_ushort(__float2half(__expf(leaky(a.z + d.z) - m.z)));
        unsigned int w3 = (unsigned int)__half_as_ushort(__float2half(__expf(leaky(a.w + d.w) - m.w)));
        pk[e]                 = (w0 << 16) | su;
        pk[(size_t)M + e]     = (w1 << 16) | su;
        pk[(size_t)2 * M + e] = (w2 << 16) | su;
        pk[(size_t)3 * M + e] = (w3 << 16) | su;
    }
}

// ---------------- aggregation v11: 2 nodes per wave, f16 gathers, packed pk ----------------
__global__ __launch_bounds__(256) void aggregate_v11(const unsigned short* __restrict__ xh,
                                                     const unsigned int* __restrict__ pk,
                                                     const int* __restrict__ row_off,
                                                     unsigned short* __restrict__ hout,
                                                     int N, int Npad, int M) {
    int i = blockIdx.x;
    int slab = i & 7;
    int h = slab >> 1;
    int t = threadIdx.x;
    int wv = t >> 6;
    int lane = t & 63;
    int slot = lane >> 4;
    int l16 = lane & 15;
    int nbase = ((i >> 3) * 4 + wv) * 2;
    if (nbase >= N) return;

    i32x4 rx = make_rsrc(xh + (size_t)slab * Npad * 64, (unsigned int)Npad * 128u);
    i32x4 rp = make_rsrc(pk + (size_t)h * M, (unsigned int)M * 4u);
    int ld8 = l16 << 3;
    int slot4 = slot << 2;
    int nend = (nbase + 2 < N) ? nbase + 2 : N;

    for (int n = nbase; n < nend; ++n) {
        int beg = row_off[n], end = row_off[n + 1];
        __half2 acc01 = u2h2(0), acc23 = u2h2(0), den2 = u2h2(0);

        for (int ebase = beg; ebase < end; ebase += 64) {
            int p = amd_buf_load_i32(rp, (ebase + lane) << 2, 0, 0);
            int nrem = end - ebase;
            int jmax = ((nrem < 64 ? nrem : 64) + 7) >> 3;
            for (int j = 0; j < jmax; ++j) {
                int addr = (j << 5) + slot4;
                int sp0 = __builtin_amdgcn_ds_bpermute(addr, p);
                int sp1 = __builtin_amdgcn_ds_bpermute(addr + 16, p);
                int e0 = ebase + (j << 3) + slot;
                i32x2 ga = amd_buf_load_i32x2(rx, ((sp0 & 0xffff) << 7) + ld8, 0, 0);
                i32x2 gb = amd_buf_load_i32x2(rx, ((sp1 & 0xffff) << 7) + ld8, 0, 0);
                unsigned int wa2 = __builtin_amdgcn_perm(sp0, sp0, 0x03020302);
                unsigned int wb2 = __builtin_amdgcn_perm(sp1, sp1, 0x03020302);
                if (e0 >= end) wa2 = 0u;
                if (e0 + 4 >= end) wb2 = 0u;
                __half2 wha = u2h2(wa2), whb = u2h2(wb2);
                acc01 = __hfma2(wha, u2h2((unsigned int)ga.x), acc01);
                acc23 = __hfma2(wha, u2h2((unsigned int)ga.y), acc23);
                acc01 = __hfma2(whb, u2h2((unsigned int)gb.x), acc01);
                acc23 = __hfma2(whb, u2h2((unsigned int)gb.y), acc23);
                den2 = __hadd2(den2, wha);
                den2 = __hadd2(den2, whb);
            }
        }

        #pragma unroll
        for (int off = 16; off <= 32; off <<= 1) {
            acc01 = __hadd2(acc01, u2h2((unsigned int)__shfl_xor((int)h22u(acc01), off)));
            acc23 = __hadd2(acc23, u2h2((unsigned int)__shfl_xor((int)h22u(acc23), off)));
            den2  = __hadd2(den2,  u2h2((unsigned int)__shfl_xor((int)h22u(den2),  off)));
        }

        if (slot == 0) {
            float2 f01 = __half22float2(acc01);
            float2 f23 = __half22float2(acc23);
            float inv = 1.f / __half2float(__low2half(den2));
            uint2 o;
            o.x = f2bf_bits(f01.x * inv) | (f2bf_bits(f01.y * inv) << 16);
            o.y = f2bf_bits(f23.x * inv) | (f2bf_bits(f23.y * inv) << 16);
            ((uint2*)hout)[((size_t)slab * Npad + n) * 16 + l16] = o;
        }
    }
}

// ---------------- head mean + bias -> bf16 feats (+ optional out init for pair) ----------------
__global__ void combine_kernel(const unsigned short* __restrict__ hout,
                               const float* __restrict__ bias,
                               unsigned short* __restrict__ featsbf, int N, int Npad,
                               float* __restrict__ out, const float* __restrict__ fcb, int P) {
    int i = blockIdx.x * blockDim.x + threadIdx.x;   // dword index over [N][64]
    if (out != nullptr && i < P) out[i] = fcb[0];
    if (i >= N * 64) return;
    int n = i >> 6, c2 = i & 63;
    int chalf = c2 >> 5, ld = c2 & 31;
    const unsigned int* hp = (const unsigned int*)hout;
    float lo = 0.f, hi = 0.f;
    #pragma unroll
    for (int h = 0; h < 4; ++h) {
        unsigned int v = hp[((size_t)(h * 2 + chalf) * Npad + n) * 32 + ld];
        lo += bflo(v); hi += bfhi(v);
    }
    lo = 0.25f * lo + bias[c2 * 2];
    hi = 0.25f * hi + bias[c2 * 2 + 1];
    ((unsigned int*)featsbf)[(size_t)n * 64 + c2] = f2bf_bits(lo) | (f2bf_bits(hi) << 16);
}

// ---------------- pairwise scorer: chalf-split, XCD parity pinned, atomic combine ----------------
__global__ __launch_bounds__(256) void pair_kernel(const unsigned short* __restrict__ featsbf,
                                                   const float* __restrict__ x,
                                                   const int* __restrict__ idx, int P,
                                                   const float* __restrict__ fc_w,
                                                   float* __restrict__ out) {
    int chalf = blockIdx.x & 1;
    int p = (blockIdx.x >> 1) * 16 + (threadIdx.x >> 4);
    int l = threadIdx.x & 15;
    if (p >= P) return;
    int i0 = idx[p], i1 = idx[P + p];
    uint2 a = ((const uint2*)featsbf)[(size_t)i0 * 32 + chalf * 16 + l];
    uint2 b = ((const uint2*)featsbf)[(size_t)i1 * 32 + chalf * 16 + l];
    float s = bflo(a.x) * bflo(b.x) + bfhi(a.x) * bfhi(b.x)
            + bflo(a.y) * bflo(b.y) + bfhi(a.y) * bfhi(b.y);
    s += __shfl_xor(s, 1); s += __shfl_xor(s, 2);
    s += __shfl_xor(s, 4); s += __shfl_xor(s, 8);
    if (l == 0) {
        float v = fc_w[0] * s;
        if (chalf == 0) {
            float2 c0 = *(const float2*)&x[(size_t)i0 * 130];
            float2 c1 = *(const float2*)&x[(size_t)i1 * 130];
            float dx = c0.x - c1.x;
            float dy = c0.y - c1.y;
            v += fc_w[1] * (dx * dx + dy * dy);
        }
        atomicAdd(&out[p], v);
    }
}

extern "C" void kernel_launch(void* const* d_in, const int* in_sizes, int n_in,
                              void* d_out, int out_size, void* d_ws, size_t ws_size,
                              hipStream_t stream) {
    const float* x   = (const float*)d_in[0];
    const int*   ei  = (const int*)d_in[1];
    const int*   idx = (const int*)d_in[2];
    const float* W1  = (const float*)d_in[3];
    const float* as1 = (const float*)d_in[4];
    const float* ad1 = (const float*)d_in[5];
    const float* b1  = (const float*)d_in[6];
    const float* W2  = (const float*)d_in[7];
    const float* as2 = (const float*)d_in[8];
    const float* ad2 = (const float*)d_in[9];
    const float* b2  = (const float*)d_in[10];
    const float* fcw = (const float*)d_in[11];
    const float* fcb = (const float*)d_in[12];
    float* out = (float*)d_out;

    const int N = in_sizes[0] / 130;
    const int E = in_sizes[1] / 2;
    const int P = in_sizes[2] / 2;
    const int M = E + N;
    const int Npad = (N + 127) & ~127;

    char* ws = (char*)d_ws;
    size_t off = 0;
    auto alloc = [&](size_t bytes) -> void* {
        void* p = ws + off;
        off += (bytes + 255) & ~(size_t)255;
        return p;
    };
    unsigned short* xh_f16  = (unsigned short*)alloc((size_t)Npad * FOUT * 2);
    unsigned short* hout    = (unsigned short*)alloc((size_t)Npad * FOUT * 2);
    unsigned short* featsbf = (unsigned short*)alloc((size_t)Npad * C * 2);
    unsigned short* Wt1     = (unsigned short*)alloc((size_t)128 * FOUT * 2);
    unsigned short* Wt2     = (unsigned short*)alloc((size_t)128 * FOUT * 2);
    float*          alpha_s = (float*)alloc((size_t)N * H * 4);
    float*          alpha_d = (float*)alloc((size_t)N * H * 4);
    unsigned int*   pk      = (unsigned int*)alloc((size_t)M * H * 4);
    int*            row_off = (int*)alloc((size_t)(N + 1) * 4);
    int*            cursor  = (int*)alloc((size_t)N * 4);
    int*            counts  = (int*)alloc((size_t)N * 4);
    int*            csr_src = (int*)alloc((size_t)M * 4);

    const int histBlocks = (M + 255) / 256;
    const int scatBlocks = (M + 255) / 256;
    const int gemmBlocks = 4 * (Npad / 128);
    int aggGrid = ((N + 7) / 8) * 8;
    int cmbGrid = (N * 64 + 255) / 256;

    // counts=0, then (weights-convert || hist), scan, (scatter || gemm1)
    hipMemsetAsync(counts, 0, (size_t)N * 4, stream);
    prep_hist<<<256 + histBlocks, 256, 0, stream>>>(W1, W2, Wt1, Wt2, counts, ei, E, N);
    scan_kernel<<<1, 1024, 0, stream>>>(counts, row_off, cursor, N);
    scatter_gemm1<<<scatBlocks + gemmBlocks, 256, 0, stream>>>(ei, E, N, cursor, csr_src,
                                                               x, Wt1, as1, ad1, xh_f16,
                                                               alpha_s, alpha_d, Npad, scatBlocks);

    // layer 1 rest
    attn_kernel<<<(N + 3) / 4, 256, 0, stream>>>((const float4*)alpha_s, (const float4*)alpha_d,
                                                 row_off, csr_src, pk, N, M);
    aggregate_v11<<<aggGrid, 256, 0, stream>>>(xh_f16, pk, row_off, hout, N, Npad, M);
    combine_kernel<<<cmbGrid, 256, 0, stream>>>(hout, b1, featsbf, N, Npad, nullptr, fcb, 0);

    // layer 2
    gemm2_kernel<<<gemmBlocks, 256, 0, stream>>>(featsbf, N, Wt2, as2, ad2, xh_f16,
                                                 alpha_s, alpha_d, Npad);
    attn_kernel<<<(N + 3) / 4, 256, 0, stream>>>((const float4*)alpha_s, (const float4*)alpha_d,
                                                 row_off, csr_src, pk, N, M);
    aggregate_v11<<<aggGrid, 256, 0, stream>>>(xh_f16, pk, row_off, hout, N, Npad, M);
    combine_kernel<<<cmbGrid, 256, 0, stream>>>(hout, b2, featsbf, N, Npad, out, fcb, P);

    // pairwise output (chalf-split, accumulates into out initialized by combine above)
    pair_kernel<<<((P + 15) / 16) * 2, 256, 0, stream>>>(featsbf, x, idx, P, fcw, out);
}